// Round 2
// baseline (465.460 us; speedup 1.0000x reference)
//
#include <hip/hip_runtime.h>

typedef __bf16 bf16;
typedef __bf16 bf16x8 __attribute__((ext_vector_type(8)));
typedef __bf16 bf16x4 __attribute__((ext_vector_type(4)));
typedef float f32x4 __attribute__((ext_vector_type(4)));

#define N_TOK 9216
#define SRC 1024
#define EDIM 256
#define NE 16384
#define GROUPS 16
#define GSIZE 1024
#define LOSS_DENOM 2359296.0f  // 16*576*256

__device__ __forceinline__ void async_load16(const void* g, void* l) {
  __builtin_amdgcn_global_load_lds(
      (__attribute__((address_space(1))) void*)(void*)(const_cast<void*>(g)),
      (__attribute__((address_space(3))) void*)l, 16, 0, 0);
}

__device__ __forceinline__ f32x4 mfma16(bf16x8 a, bf16x8 b, f32x4 c) {
  return __builtin_amdgcn_mfma_f32_16x16x32_bf16(a, b, c, 0, 0, 0);
}

// ---------------- prep kernels ----------------

__global__ __launch_bounds__(256) void k_cast_x(const float* __restrict__ x,
                                                bf16* __restrict__ xb,
                                                float* __restrict__ lacc) {
  int i = blockIdx.x * 256 + threadIdx.x;
  float4 v = ((const float4*)x)[i];
  bf16x4 o = {(bf16)v.x, (bf16)v.y, (bf16)v.z, (bf16)v.w};
  *(bf16x4*)(xb + 4 * i) = o;
  if (i == 0) *lacc = 0.f;
}

__global__ __launch_bounds__(256) void k_prep_w(const float* __restrict__ enc_w,
                                                const float* __restrict__ dec_w,
                                                bf16* __restrict__ enc_wT,
                                                bf16* __restrict__ dec_wT) {
  int id = blockIdx.x * 256 + threadIdx.x;
  {
    int n = id >> 10, k = id & 1023;
    enc_wT[id] = (bf16)enc_w[k * EDIM + n];
  }
  {
    int n = id >> 8, k = id & 255;
    dec_wT[id] = (bf16)dec_w[k * SRC + n];
  }
}

__global__ __launch_bounds__(256) void k_prep_cb(const float* __restrict__ cb,
                                                 bf16* __restrict__ cbb,
                                                 float* __restrict__ e2) {
  int row = blockIdx.x * 4 + (threadIdx.x >> 6);
  int lane = threadIdx.x & 63;
  float4 v = ((const float4*)(cb + (size_t)row * EDIM))[lane];
  bf16x4 o = {(bf16)v.x, (bf16)v.y, (bf16)v.z, (bf16)v.w};
  *(bf16x4*)(cbb + (size_t)row * EDIM + lane * 4) = o;
  float s = v.x * v.x + v.y * v.y + v.z * v.z + v.w * v.w;
#pragma unroll
  for (int off = 32; off; off >>= 1) s += __shfl_xor(s, off, 64);
  if (lane == 0) e2[row] = s;
}

// ---------------- 128x128 bf16 MFMA GEMM (m97 structure) ----------------
// C[M,N] = A[M,K] * BT[N,K]^T + bias. 4 waves in 2x2, each 64x64 (4x4 of 16x16x32).
// LDS granule (row, gs) holds global granule gs ^ (row&3)  (16B granules, 4/row).
__global__ __launch_bounds__(256) void k_gemm128(const bf16* __restrict__ A,
                                                 const bf16* __restrict__ BT,
                                                 const float* __restrict__ bias,
                                                 float* __restrict__ Cf,
                                                 bf16* __restrict__ Cb, int K, int N) {
  __shared__ __align__(16) bf16 As[128 * 32];
  __shared__ __align__(16) bf16 Bs[128 * 32];
  const int tid = threadIdx.x;
  const int wid = tid >> 6, lane = tid & 63;
  const int col = lane & 15, quad = lane >> 4;
  const int wm = (wid >> 1) * 64, wn = (wid & 1) * 64;
  const int bm = blockIdx.x * 128, bn = blockIdx.y * 128;
  // staging: 512 granules per matrix, 2 instrs per thread per matrix
  const int srow = (wid * 128 + lane) >> 2;  // rows for j=0; j=1 adds 16
  const int sgs = lane & 3;
  f32x4 acc[4][4] = {};
  for (int kc = 0; kc < K; kc += 32) {
#pragma unroll
    for (int j = 0; j < 2; j++) {
      int row = srow + j * 16;
      int gg = sgs ^ (row & 3);
      const bf16* ag = A + (size_t)(bm + row) * K + kc + gg * 8;
      const bf16* bg = BT + (size_t)(bn + row) * K + kc + gg * 8;
      async_load16(ag, (char*)As + wid * 2048 + j * 1024);
      async_load16(bg, (char*)Bs + wid * 2048 + j * 1024);
    }
    __syncthreads();
    bf16x8 afr[4], bfr[4];
#pragma unroll
    for (int t = 0; t < 4; t++) {
      int row = wm + t * 16 + col;
      afr[t] = *(const bf16x8*)((const char*)As + (row * 4 + (quad ^ (row & 3))) * 16);
    }
#pragma unroll
    for (int u = 0; u < 4; u++) {
      int row = wn + u * 16 + col;
      bfr[u] = *(const bf16x8*)((const char*)Bs + (row * 4 + (quad ^ (row & 3))) * 16);
    }
#pragma unroll
    for (int t = 0; t < 4; t++)
#pragma unroll
      for (int u = 0; u < 4; u++) acc[t][u] = mfma16(afr[t], bfr[u], acc[t][u]);
    __syncthreads();
  }
#pragma unroll
  for (int u = 0; u < 4; u++) {
    int n = bn + wn + u * 16 + col;
    float bv = bias[n];
#pragma unroll
    for (int t = 0; t < 4; t++) {
#pragma unroll
      for (int r = 0; r < 4; r++) {
        int m = bm + wm + t * 16 + quad * 4 + r;
        float v = acc[t][u][r] + bv;
        Cf[(size_t)m * N + n] = v;
        if (Cb) Cb[(size_t)m * N + n] = (bf16)v;
      }
    }
  }
}

// ---------------- fused cross-GEMM + argmin v2 ----------------
// Block: 256 tokens x 1024-code group. 4 waves, each 64 tokens (af[4][8] in regs).
// Stage = 64 codes (32 KB), double-buffered, ONE barrier per stage.
__global__ __launch_bounds__(256, 2) void k_argmin(const bf16* __restrict__ zb,
                                                   const bf16* __restrict__ cbb,
                                                   const float* __restrict__ e2,
                                                   float* __restrict__ pval,
                                                   int* __restrict__ pidx) {
  __shared__ __align__(16) bf16 Cs[2 * 64 * 256];  // 65536 B
  const int tid = threadIdx.x;
  const int wid = tid >> 6, lane = tid & 63;
  const int col = lane & 15, quad = lane >> 4;
  const int g = blockIdx.y;
  const int tw = blockIdx.x * 256 + wid * 64;

  // A fragments: 4 m-tiles x 8 k-steps, register-resident for entire kernel
  bf16x8 af[4][8];
#pragma unroll
  for (int t = 0; t < 4; t++)
#pragma unroll
    for (int s = 0; s < 8; s++)
      af[t][s] = *(const bf16x8*)&zb[(size_t)(tw + t * 16 + col) * EDIM + s * 32 + quad * 8];

  float bestv[4][4];
  int besti[4][4];
#pragma unroll
  for (int t = 0; t < 4; t++)
#pragma unroll
    for (int r = 0; r < 4; r++) { bestv[t][r] = 3.4e38f; besti[t][r] = 0; }

  // staging constants: wave w loads rows [w*16, w*16+16) of the 64-code stage
  const int srow0 = wid * 16 + (lane >> 5);  // + j*2
  const int sgs = lane & 31;

  auto stage_load = [&](int st, int b) {
    const bf16* src = cbb + (size_t)(g * GSIZE + st * 64) * EDIM;
    char* base = (char*)Cs + b * 32768 + wid * 8192;
#pragma unroll
    for (int j = 0; j < 8; j++) {
      int row = srow0 + j * 2;
      int gg = sgs ^ (row & 31);
      async_load16(src + (size_t)row * EDIM + gg * 8, base + j * 1024);
    }
  };

  auto compute = [&](int st, int b) {
    const char* bbase = (const char*)Cs + b * 32768;
    f32x4 c[4][4] = {};
#pragma unroll
    for (int s = 0; s < 8; s++) {
      bf16x8 bb[4];
#pragma unroll
      for (int u = 0; u < 4; u++) {
        int row = u * 16 + col;
        bb[u] = *(const bf16x8*)(bbase + (row * 32 + ((s * 4 + quad) ^ (row & 31))) * 16);
      }
#pragma unroll
      for (int t = 0; t < 4; t++)
#pragma unroll
        for (int u = 0; u < 4; u++) c[t][u] = mfma16(af[t][s], bb[u], c[t][u]);
    }
    const int cb0 = g * GSIZE + st * 64;
#pragma unroll
    for (int u = 0; u < 4; u++) {
      float ev = e2[cb0 + u * 16 + col];
      int code = cb0 + u * 16 + col;
#pragma unroll
      for (int t = 0; t < 4; t++)
#pragma unroll
        for (int r = 0; r < 4; r++) {
          float d = ev - 2.f * c[t][u][r];
          if (d < bestv[t][r]) { bestv[t][r] = d; besti[t][r] = code; }
        }
    }
  };

  stage_load(0, 0);
  for (int st = 0; st < 16; st++) {
    __syncthreads();  // stage-st data ready (vmcnt drain); prev buffer fully consumed
    if (st < 15) stage_load(st + 1, (st + 1) & 1);
    compute(st, st & 1);
  }

  // reduce across 16 cols (lanes sharing quad)
#pragma unroll
  for (int off = 1; off < 16; off <<= 1) {
#pragma unroll
    for (int t = 0; t < 4; t++)
#pragma unroll
      for (int r = 0; r < 4; r++) {
        float ov = __shfl_xor(bestv[t][r], off, 64);
        int oi = __shfl_xor(besti[t][r], off, 64);
        if (ov < bestv[t][r] || (ov == bestv[t][r] && oi < besti[t][r])) {
          bestv[t][r] = ov;
          besti[t][r] = oi;
        }
      }
  }
  if (col == 0) {
#pragma unroll
    for (int t = 0; t < 4; t++)
#pragma unroll
      for (int r = 0; r < 4; r++) {
        int token = tw + t * 16 + quad * 4 + r;
        pval[token * GROUPS + g] = bestv[t][r];
        pidx[token * GROUPS + g] = besti[t][r];
      }
  }
}

// ---------------- gather + loss partial ----------------
__global__ __launch_bounds__(256) void k_gather(const float* __restrict__ cb,
                                                const float* __restrict__ zf,
                                                const float* __restrict__ pval,
                                                const int* __restrict__ pidx,
                                                bf16* __restrict__ zqb,
                                                float* __restrict__ lacc) {
  int token = blockIdx.x * 4 + (threadIdx.x >> 6);
  int lane = threadIdx.x & 63;
  float v = 3.4e38f;
  int idx = 0;
  if (lane < 16) {
    v = pval[token * GROUPS + lane];
    idx = pidx[token * GROUPS + lane];
  }
#pragma unroll
  for (int off = 1; off < 16; off <<= 1) {
    float ov = __shfl_xor(v, off, 64);
    int oi = __shfl_xor(idx, off, 64);
    if (ov < v || (ov == v && oi < idx)) { v = ov; idx = oi; }
  }
  idx = __shfl(idx, 0, 64);
  float4 q = ((const float4*)(cb + (size_t)idx * EDIM))[lane];
  float4 z = ((const float4*)(zf + (size_t)token * EDIM))[lane];
  bf16x4 o = {(bf16)q.x, (bf16)q.y, (bf16)q.z, (bf16)q.w};
  *(bf16x4*)(zqb + (size_t)token * EDIM + lane * 4) = o;
  float dx = q.x - z.x, dy = q.y - z.y, dz = q.z - z.z, dw = q.w - z.w;
  float s = dx * dx + dy * dy + dz * dz + dw * dw;
#pragma unroll
  for (int off = 32; off; off >>= 1) s += __shfl_xor(s, off, 64);
  if (lane == 0) atomicAdd(lacc, s);
}

__global__ void k_loss(const float* __restrict__ lacc, float* __restrict__ outl) {
  *outl = 1.25f * (*lacc) / LOSS_DENOM;
}

// ---------------- launch ----------------
extern "C" void kernel_launch(void* const* d_in, const int* in_sizes, int n_in,
                              void* d_out, int out_size, void* d_ws, size_t ws_size,
                              hipStream_t stream) {
  const float* x = (const float*)d_in[0];
  const float* enc_w = (const float*)d_in[1];
  const float* enc_b = (const float*)d_in[2];
  const float* cb = (const float*)d_in[3];
  const float* dec_w = (const float*)d_in[4];
  const float* dec_b = (const float*)d_in[5];
  float* out = (float*)d_out;
  float* out_loss = out + (size_t)N_TOK * SRC;

  char* ws = (char*)d_ws;
  bf16* xb = (bf16*)(ws + 0);              // 18,874,368 B
  bf16* enc_wT = (bf16*)(ws + 18874368);   //    524,288 B
  bf16* dec_wT = (bf16*)(ws + 19398656);   //    524,288 B
  float* zf = (float*)(ws + 19922944);     //  9,437,184 B
  bf16* zb = (bf16*)(ws + 29360128);       //  4,718,592 B
  bf16* cbb = (bf16*)(ws + 34078720);      //  8,388,608 B
  float* e2 = (float*)(ws + 42467328);     //     65,536 B
  float* pval = (float*)(ws + 42532864);   //    589,824 B
  int* pidx = (int*)(ws + 43122688);       //    589,824 B
  bf16* zqb = (bf16*)(ws + 43712512);      //  4,718,592 B
  float* lacc = (float*)(ws + 48431104);   //          4 B

  k_cast_x<<<9216, 256, 0, stream>>>(x, xb, lacc);
  k_prep_w<<<1024, 256, 0, stream>>>(enc_w, dec_w, enc_wT, dec_wT);
  k_prep_cb<<<4096, 256, 0, stream>>>(cb, cbb, e2);
  // encoder: z = x @ enc_w + enc_b  (M=9216, K=1024, N=256)
  k_gemm128<<<dim3(72, 2), 256, 0, stream>>>(xb, enc_wT, enc_b, zf, zb, 1024, 256);
  // fused distance + argmin
  k_argmin<<<dim3(36, GROUPS), 256, 0, stream>>>(zb, cbb, e2, pval, pidx);
  k_gather<<<2304, 256, 0, stream>>>(cb, zf, pval, pidx, zqb, lacc);
  // decoder: out = z_q @ dec_w + dec_b  (M=9216, K=256, N=1024)
  k_gemm128<<<dim3(72, 8), 256, 0, stream>>>(zqb, dec_wT, dec_b, out, nullptr, 256, 1024);
  k_loss<<<1, 1, 0, stream>>>(lacc, out_loss);
}

// Round 3
// 256.633 us; speedup vs baseline: 1.8137x; 1.8137x over previous
//
#include <hip/hip_runtime.h>

typedef __bf16 bf16;
typedef __bf16 bf16x8 __attribute__((ext_vector_type(8)));
typedef __bf16 bf16x4 __attribute__((ext_vector_type(4)));
typedef float f32x4 __attribute__((ext_vector_type(4)));

#define N_TOK 9216
#define SRC 1024
#define EDIM 256
#define NE 16384
#define GROUPS 16
#define GSIZE 1024
#define NBLK_GATHER 2304
#define LOSS_DENOM 2359296.0f  // 16*576*256

__device__ __forceinline__ void async_load16(const void* g, void* l) {
  __builtin_amdgcn_global_load_lds(
      (__attribute__((address_space(1))) void*)(void*)(const_cast<void*>(g)),
      (__attribute__((address_space(3))) void*)l, 16, 0, 0);
}

__device__ __forceinline__ f32x4 mfma16(bf16x8 a, bf16x8 b, f32x4 c) {
  return __builtin_amdgcn_mfma_f32_16x16x32_bf16(a, b, c, 0, 0, 0);
}

// ---------------- prep kernels ----------------

__global__ __launch_bounds__(256) void k_cast_x(const float* __restrict__ x,
                                                bf16* __restrict__ xb) {
  int i = blockIdx.x * 256 + threadIdx.x;
  float4 v = ((const float4*)x)[i];
  bf16x4 o = {(bf16)v.x, (bf16)v.y, (bf16)v.z, (bf16)v.w};
  *(bf16x4*)(xb + 4 * i) = o;
}

__global__ __launch_bounds__(256) void k_prep_w(const float* __restrict__ enc_w,
                                                const float* __restrict__ dec_w,
                                                bf16* __restrict__ enc_wT,
                                                bf16* __restrict__ dec_wT) {
  int id = blockIdx.x * 256 + threadIdx.x;
  {
    int n = id >> 10, k = id & 1023;
    enc_wT[id] = (bf16)enc_w[k * EDIM + n];
  }
  {
    int n = id >> 8, k = id & 255;
    dec_wT[id] = (bf16)dec_w[k * SRC + n];
  }
}

__global__ __launch_bounds__(256) void k_prep_cb(const float* __restrict__ cb,
                                                 bf16* __restrict__ cbb,
                                                 float* __restrict__ e2) {
  int row = blockIdx.x * 4 + (threadIdx.x >> 6);
  int lane = threadIdx.x & 63;
  float4 v = ((const float4*)(cb + (size_t)row * EDIM))[lane];
  bf16x4 o = {(bf16)v.x, (bf16)v.y, (bf16)v.z, (bf16)v.w};
  *(bf16x4*)(cbb + (size_t)row * EDIM + lane * 4) = o;
  float s = v.x * v.x + v.y * v.y + v.z * v.z + v.w * v.w;
#pragma unroll
  for (int off = 32; off; off >>= 1) s += __shfl_xor(s, off, 64);
  if (lane == 0) e2[row] = s;
}

// ---------------- 128xBN bf16 MFMA GEMM (m97 structure) ----------------
// C = A[M,K] * BT[N,K]^T + bias. 4 waves 2x2; wave tile 64 x (BN/2).
// LDS granule (row, g) holds global granule g ^ (row&3).
template <int BN>
__global__ __launch_bounds__(256) void k_gemm(const bf16* __restrict__ A,
                                              const bf16* __restrict__ BT,
                                              const float* __restrict__ bias,
                                              float* __restrict__ Cf,
                                              bf16* __restrict__ Cb, int K, int N) {
  __shared__ __align__(16) bf16 As[128 * 32];
  __shared__ __align__(16) bf16 Bs[BN * 32];
  const int tid = threadIdx.x;
  const int wid = tid >> 6, lane = tid & 63;
  const int col = lane & 15, quad = lane >> 4;
  constexpr int WN = BN / 2, UN = BN / 32;
  const int wm = (wid >> 1) * 64, wn = (wid & 1) * WN;
  const int bm = blockIdx.x * 128, bn = blockIdx.y * BN;
  f32x4 acc[4][UN] = {};
  for (int kc = 0; kc < K; kc += 32) {
    // A: 512 granules, 2 instrs/wave
#pragma unroll
    for (int j = 0; j < 2; j++) {
      int slot = wid * 128 + j * 64 + lane;
      int row = slot >> 2;
      int gg = (slot & 3) ^ (row & 3);
      async_load16(A + (size_t)(bm + row) * K + kc + gg * 8,
                   (char*)As + wid * 2048 + j * 1024);
    }
    // B: BN*4 granules
#pragma unroll
    for (int j = 0; j < BN / 64; j++) {
      int slot = wid * (BN / 64) * 64 + j * 64 + lane;
      int row = slot >> 2;
      int gg = (slot & 3) ^ (row & 3);
      async_load16(BT + (size_t)(bn + row) * K + kc + gg * 8,
                   (char*)Bs + wid * (BN / 64) * 1024 + j * 1024);
    }
    __syncthreads();
    bf16x8 afr[4], bfr[UN];
#pragma unroll
    for (int t = 0; t < 4; t++) {
      int row = wm + t * 16 + col;
      afr[t] = *(const bf16x8*)((const char*)As + (row * 4 + (quad ^ (row & 3))) * 16);
    }
#pragma unroll
    for (int u = 0; u < UN; u++) {
      int row = wn + u * 16 + col;
      bfr[u] = *(const bf16x8*)((const char*)Bs + (row * 4 + (quad ^ (row & 3))) * 16);
    }
#pragma unroll
    for (int t = 0; t < 4; t++)
#pragma unroll
      for (int u = 0; u < UN; u++) acc[t][u] = mfma16(afr[t], bfr[u], acc[t][u]);
    __syncthreads();
  }
#pragma unroll
  for (int u = 0; u < UN; u++) {
    int n = bn + wn + u * 16 + col;
    float bv = bias[n];
#pragma unroll
    for (int t = 0; t < 4; t++) {
#pragma unroll
      for (int r = 0; r < 4; r++) {
        int m = bm + wm + t * 16 + quad * 4 + r;
        float v = acc[t][u][r] + bv;
        Cf[(size_t)m * N + n] = v;
        if (Cb) Cb[(size_t)m * N + n] = (bf16)v;
      }
    }
  }
}

// ---------------- fused cross-GEMM + argmin v3 ----------------
// Block: 128 tokens x 1024-code group. 4 waves, each 32 tokens (af[2][8] = 64 VGPR).
// Stage = 64 codes (32 KB), double-buffered (64 KB LDS, 2 blocks/CU), 1 barrier/stage.
__global__ __launch_bounds__(256, 2) void k_argmin(const bf16* __restrict__ zb,
                                                   const bf16* __restrict__ cbb,
                                                   const float* __restrict__ e2,
                                                   float* __restrict__ pval,
                                                   int* __restrict__ pidx) {
  __shared__ __align__(16) bf16 Cs[2 * 64 * 256];  // 65536 B
  const int tid = threadIdx.x;
  const int wid = tid >> 6, lane = tid & 63;
  const int col = lane & 15, quad = lane >> 4;
  const int g = blockIdx.y;
  const int tw = blockIdx.x * 128 + wid * 32;

  bf16x8 af[2][8];
#pragma unroll
  for (int t = 0; t < 2; t++)
#pragma unroll
    for (int s = 0; s < 8; s++)
      af[t][s] = *(const bf16x8*)&zb[(size_t)(tw + t * 16 + col) * EDIM + s * 32 + quad * 8];

  float bestv[2][4];
  int besti[2][4];
#pragma unroll
  for (int t = 0; t < 2; t++)
#pragma unroll
    for (int r = 0; r < 4; r++) { bestv[t][r] = 3.4e38f; besti[t][r] = 0; }

  // staging: 2048 granules/stage; wave covers 16 rows (512 granules, 8 instrs)
  const int srow0 = wid * 16 + (lane >> 5);
  const int sgs = lane & 31;

  auto stage_load = [&](int st, int b) {
    const bf16* src = cbb + (size_t)(g * GSIZE + st * 64) * EDIM;
    char* base = (char*)Cs + b * 32768 + wid * 8192;
#pragma unroll
    for (int j = 0; j < 8; j++) {
      int row = srow0 + j * 2;
      int gg = sgs ^ (row & 31);
      async_load16(src + (size_t)row * EDIM + gg * 8, base + j * 1024);
    }
  };

  auto compute = [&](int st, int b) {
    const char* bbase = (const char*)Cs + b * 32768;
    f32x4 c[2][4] = {};
#pragma unroll
    for (int s = 0; s < 8; s++) {
      bf16x8 bb[4];
#pragma unroll
      for (int u = 0; u < 4; u++) {
        int row = u * 16 + col;
        bb[u] = *(const bf16x8*)(bbase + (row * 32 + ((s * 4 + quad) ^ (row & 31))) * 16);
      }
#pragma unroll
      for (int t = 0; t < 2; t++)
#pragma unroll
        for (int u = 0; u < 4; u++) c[t][u] = mfma16(af[t][s], bb[u], c[t][u]);
    }
    const int cb0 = g * GSIZE + st * 64;
#pragma unroll
    for (int u = 0; u < 4; u++) {
      float ev = e2[cb0 + u * 16 + col];
      int code = cb0 + u * 16 + col;
#pragma unroll
      for (int t = 0; t < 2; t++)
#pragma unroll
        for (int r = 0; r < 4; r++) {
          float d = ev - 2.f * c[t][u][r];
          if (d < bestv[t][r]) { bestv[t][r] = d; besti[t][r] = code; }
        }
    }
  };

  stage_load(0, 0);
  for (int st = 0; st < 16; st++) {
    __syncthreads();  // stage st landed (vmcnt drain) + prev buffer consumed
    if (st < 15) stage_load(st + 1, (st + 1) & 1);
    compute(st, st & 1);
  }

#pragma unroll
  for (int off = 1; off < 16; off <<= 1) {
#pragma unroll
    for (int t = 0; t < 2; t++)
#pragma unroll
      for (int r = 0; r < 4; r++) {
        float ov = __shfl_xor(bestv[t][r], off, 64);
        int oi = __shfl_xor(besti[t][r], off, 64);
        if (ov < bestv[t][r] || (ov == bestv[t][r] && oi < besti[t][r])) {
          bestv[t][r] = ov;
          besti[t][r] = oi;
        }
      }
  }
  if (col == 0) {
#pragma unroll
    for (int t = 0; t < 2; t++)
#pragma unroll
      for (int r = 0; r < 4; r++) {
        int token = tw + t * 16 + quad * 4 + r;
        pval[token * GROUPS + g] = bestv[t][r];
        pidx[token * GROUPS + g] = besti[t][r];
      }
  }
}

// ---------------- gather + per-block loss partial (no global atomics) --------
__global__ __launch_bounds__(256) void k_gather(const float* __restrict__ cb,
                                                const float* __restrict__ zf,
                                                const float* __restrict__ pval,
                                                const int* __restrict__ pidx,
                                                bf16* __restrict__ zqb,
                                                float* __restrict__ lpart) {
  __shared__ float ls[4];
  int wv = threadIdx.x >> 6;
  int token = blockIdx.x * 4 + wv;
  int lane = threadIdx.x & 63;
  float v = 3.4e38f;
  int idx = 0;
  if (lane < 16) {
    v = pval[token * GROUPS + lane];
    idx = pidx[token * GROUPS + lane];
  }
#pragma unroll
  for (int off = 1; off < 16; off <<= 1) {
    float ov = __shfl_xor(v, off, 64);
    int oi = __shfl_xor(idx, off, 64);
    if (ov < v || (ov == v && oi < idx)) { v = ov; idx = oi; }
  }
  idx = __shfl(idx, 0, 64);
  float4 q = ((const float4*)(cb + (size_t)idx * EDIM))[lane];
  float4 z = ((const float4*)(zf + (size_t)token * EDIM))[lane];
  bf16x4 o = {(bf16)q.x, (bf16)q.y, (bf16)q.z, (bf16)q.w};
  *(bf16x4*)(zqb + (size_t)token * EDIM + lane * 4) = o;
  float dx = q.x - z.x, dy = q.y - z.y, dz = q.z - z.z, dw = q.w - z.w;
  float s = dx * dx + dy * dy + dz * dz + dw * dw;
#pragma unroll
  for (int off = 32; off; off >>= 1) s += __shfl_xor(s, off, 64);
  if (lane == 0) ls[wv] = s;
  __syncthreads();
  if (threadIdx.x == 0) lpart[blockIdx.x] = ls[0] + ls[1] + ls[2] + ls[3];
}

__global__ __launch_bounds__(256) void k_loss(const float* __restrict__ lpart,
                                              float* __restrict__ outl) {
  __shared__ float ls[4];
  float s = 0.f;
  for (int i = threadIdx.x; i < NBLK_GATHER; i += 256) s += lpart[i];
#pragma unroll
  for (int off = 32; off; off >>= 1) s += __shfl_xor(s, off, 64);
  int wv = threadIdx.x >> 6;
  if ((threadIdx.x & 63) == 0) ls[wv] = s;
  __syncthreads();
  if (threadIdx.x == 0) *outl = 1.25f * (ls[0] + ls[1] + ls[2] + ls[3]) / LOSS_DENOM;
}

// ---------------- launch ----------------
extern "C" void kernel_launch(void* const* d_in, const int* in_sizes, int n_in,
                              void* d_out, int out_size, void* d_ws, size_t ws_size,
                              hipStream_t stream) {
  const float* x = (const float*)d_in[0];
  const float* enc_w = (const float*)d_in[1];
  const float* enc_b = (const float*)d_in[2];
  const float* cb = (const float*)d_in[3];
  const float* dec_w = (const float*)d_in[4];
  const float* dec_b = (const float*)d_in[5];
  float* out = (float*)d_out;
  float* out_loss = out + (size_t)N_TOK * SRC;

  char* ws = (char*)d_ws;
  bf16* xb = (bf16*)(ws + 0);              // 18,874,368 B
  bf16* enc_wT = (bf16*)(ws + 18874368);   //    524,288 B
  bf16* dec_wT = (bf16*)(ws + 19398656);   //    524,288 B
  float* zf = (float*)(ws + 19922944);     //  9,437,184 B
  bf16* zb = (bf16*)(ws + 29360128);       //  4,718,592 B
  bf16* cbb = (bf16*)(ws + 34078720);      //  8,388,608 B
  float* e2 = (float*)(ws + 42467328);     //     65,536 B
  float* pval = (float*)(ws + 42532864);   //    589,824 B
  int* pidx = (int*)(ws + 43122688);       //    589,824 B
  bf16* zqb = (bf16*)(ws + 43712512);      //  4,718,592 B
  float* lpart = (float*)(ws + 48431104);  //      9,216 B

  k_cast_x<<<9216, 256, 0, stream>>>(x, xb);
  k_prep_w<<<1024, 256, 0, stream>>>(enc_w, dec_w, enc_wT, dec_wT);
  k_prep_cb<<<4096, 256, 0, stream>>>(cb, cbb, e2);
  // encoder: z = x @ enc_w + enc_b  (M=9216, K=1024, N=256), 128x64 tiles -> 288 blocks
  k_gemm<64><<<dim3(72, 4), 256, 0, stream>>>(xb, enc_wT, enc_b, zf, zb, 1024, 256);
  // fused distance + argmin
  k_argmin<<<dim3(72, GROUPS), 256, 0, stream>>>(zb, cbb, e2, pval, pidx);
  k_gather<<<NBLK_GATHER, 256, 0, stream>>>(cb, zf, pval, pidx, zqb, lpart);
  // decoder: out = z_q @ dec_w + dec_b  (M=9216, K=256, N=1024), 128x128 tiles
  k_gemm<128><<<dim3(72, 8), 256, 0, stream>>>(zqb, dec_wT, dec_b, out, nullptr, 256, 1024);
  k_loss<<<1, 256, 0, stream>>>(lpart, out_loss);
}

// Round 4
// 230.618 us; speedup vs baseline: 2.0183x; 1.1128x over previous
//
#include <hip/hip_runtime.h>

typedef __bf16 bf16;
typedef __bf16 bf16x8 __attribute__((ext_vector_type(8)));
typedef __bf16 bf16x4 __attribute__((ext_vector_type(4)));
typedef float f32x4 __attribute__((ext_vector_type(4)));
typedef unsigned int u32;

#define N_TOK 9216
#define SRC 1024
#define EDIM 256
#define NE 16384
#define GROUPS 16
#define GSIZE 1024
#define NBLK_GATHER 2304
#define LOSS_DENOM 2359296.0f  // 16*576*256

__device__ __forceinline__ void async_load16(const void* g, void* l) {
  __builtin_amdgcn_global_load_lds(
      (__attribute__((address_space(1))) void*)(void*)(const_cast<void*>(g)),
      (__attribute__((address_space(3))) void*)l, 16, 0, 0);
}

__device__ __forceinline__ f32x4 mfma16(bf16x8 a, bf16x8 b, f32x4 c) {
  return __builtin_amdgcn_mfma_f32_16x16x32_bf16(a, b, c, 0, 0, 0);
}

// ---------------- merged prep: cast x, transpose weights, codebook cast + ||e||^2+1
__global__ __launch_bounds__(256) void k_prep(const float* __restrict__ x,
                                              const float* __restrict__ enc_w,
                                              const float* __restrict__ dec_w,
                                              const float* __restrict__ cb,
                                              bf16* __restrict__ xb,
                                              bf16* __restrict__ enc_wT,
                                              bf16* __restrict__ dec_wT,
                                              bf16* __restrict__ cbb,
                                              float* __restrict__ e2p) {
  int b = blockIdx.x;
  if (b < 9216) {  // cast x: float4 per thread
    int i = b * 256 + threadIdx.x;
    float4 v = ((const float4*)x)[i];
    bf16x4 o = {(bf16)v.x, (bf16)v.y, (bf16)v.z, (bf16)v.w};
    *(bf16x4*)(xb + 4 * i) = o;
  } else if (b < 10240) {  // weight transposes
    int id = (b - 9216) * 256 + threadIdx.x;
    {
      int n = id >> 10, k = id & 1023;
      enc_wT[id] = (bf16)enc_w[k * EDIM + n];
    }
    {
      int n = id >> 8, k = id & 255;
      dec_wT[id] = (bf16)dec_w[k * SRC + n];
    }
  } else {  // codebook: 4 rows per block, one wave each
    int row = (b - 10240) * 4 + (threadIdx.x >> 6);
    int lane = threadIdx.x & 63;
    float4 v = ((const float4*)(cb + (size_t)row * EDIM))[lane];
    bf16x4 o = {(bf16)v.x, (bf16)v.y, (bf16)v.z, (bf16)v.w};
    *(bf16x4*)(cbb + (size_t)row * EDIM + lane * 4) = o;
    float s = v.x * v.x + v.y * v.y + v.z * v.z + v.w * v.w;
#pragma unroll
    for (int off = 32; off; off >>= 1) s += __shfl_xor(s, off, 64);
    if (lane == 0) e2p[row] = s + 1.0f;  // +1 bias keeps packed keys positive
  }
}

// ---------------- 128xBN bf16 MFMA GEMM ----------------
// C = A[M,K] * BT[N,K]^T + bias. 4 waves 2x2; wave tile 64 x (BN/2).
// LDS granule (row, g) holds global granule g ^ (row&3).
template <int BN>
__global__ __launch_bounds__(256) void k_gemm(const bf16* __restrict__ A,
                                              const bf16* __restrict__ BT,
                                              const float* __restrict__ bias,
                                              float* __restrict__ Cf,
                                              bf16* __restrict__ Cb, int K, int N) {
  __shared__ __align__(16) bf16 As[128 * 32];
  __shared__ __align__(16) bf16 Bs[BN * 32];
  const int tid = threadIdx.x;
  const int wid = tid >> 6, lane = tid & 63;
  const int col = lane & 15, quad = lane >> 4;
  constexpr int WN = BN / 2, UN = BN / 32;
  const int wm = (wid >> 1) * 64, wn = (wid & 1) * WN;
  const int bm = blockIdx.x * 128, bn = blockIdx.y * BN;
  f32x4 acc[4][UN] = {};
  for (int kc = 0; kc < K; kc += 32) {
#pragma unroll
    for (int j = 0; j < 2; j++) {
      int slot = wid * 128 + j * 64 + lane;
      int row = slot >> 2;
      int gg = (slot & 3) ^ (row & 3);
      async_load16(A + (size_t)(bm + row) * K + kc + gg * 8,
                   (char*)As + wid * 2048 + j * 1024);
    }
#pragma unroll
    for (int j = 0; j < BN / 64; j++) {
      int slot = wid * (BN / 64) * 64 + j * 64 + lane;
      int row = slot >> 2;
      int gg = (slot & 3) ^ (row & 3);
      async_load16(BT + (size_t)(bn + row) * K + kc + gg * 8,
                   (char*)Bs + wid * (BN / 64) * 1024 + j * 1024);
    }
    __syncthreads();
    bf16x8 afr[4], bfr[UN];
#pragma unroll
    for (int t = 0; t < 4; t++) {
      int row = wm + t * 16 + col;
      afr[t] = *(const bf16x8*)((const char*)As + (row * 4 + (quad ^ (row & 3))) * 16);
    }
#pragma unroll
    for (int u = 0; u < UN; u++) {
      int row = wn + u * 16 + col;
      bfr[u] = *(const bf16x8*)((const char*)Bs + (row * 4 + (quad ^ (row & 3))) * 16);
    }
#pragma unroll
    for (int t = 0; t < 4; t++)
#pragma unroll
      for (int u = 0; u < UN; u++) acc[t][u] = mfma16(afr[t], bfr[u], acc[t][u]);
    __syncthreads();
  }
#pragma unroll
  for (int u = 0; u < UN; u++) {
    int n = bn + wn + u * 16 + col;
    float bv = bias[n];
#pragma unroll
    for (int t = 0; t < 4; t++) {
#pragma unroll
      for (int r = 0; r < 4; r++) {
        int m = bm + wm + t * 16 + quad * 4 + r;
        float v = acc[t][u][r] + bv;
        if (Cf) Cf[(size_t)m * N + n] = v;
        if (Cb) Cb[(size_t)m * N + n] = (bf16)v;
      }
    }
  }
}

// ---------------- fused cross-GEMM + argmin v4 ----------------
// Block: 192 tokens x 1024-code group. 4 waves, each 48 tokens (af[3][8] = 96 VGPR).
// Stage = 64 codes (32 KB), double-buffered, 1 barrier/stage.
// Packed-key argmin: d' = (e2+1) - 2*cross is positive => IEEE bits order as uint;
// low 6 mantissa bits carry candidate id (stage*4+u); update = single v_min_u32.
__global__ __launch_bounds__(256, 2) void k_argmin(const bf16* __restrict__ zb,
                                                   const bf16* __restrict__ cbb,
                                                   const float* __restrict__ e2p,
                                                   float* __restrict__ pval,
                                                   int* __restrict__ pidx) {
  __shared__ __align__(16) bf16 Cs[2 * 64 * 256];  // 65536 B
  const int tid = threadIdx.x;
  const int wid = tid >> 6, lane = tid & 63;
  const int col = lane & 15, quad = lane >> 4;
  const int g = blockIdx.y;
  const int tw = blockIdx.x * 192 + wid * 48;

  bf16x8 af[3][8];
#pragma unroll
  for (int t = 0; t < 3; t++)
#pragma unroll
    for (int s = 0; s < 8; s++)
      af[t][s] = *(const bf16x8*)&zb[(size_t)(tw + t * 16 + col) * EDIM + s * 32 + quad * 8];

  u32 best[3][4];
#pragma unroll
  for (int t = 0; t < 3; t++)
#pragma unroll
    for (int r = 0; r < 4; r++) best[t][r] = 0xFFFFFFFFu;

  const int srow0 = wid * 16 + (lane >> 5);
  const int sgs = lane & 31;

  auto stage_load = [&](int st, int b) {
    const bf16* src = cbb + (size_t)(g * GSIZE + st * 64) * EDIM;
    char* base = (char*)Cs + b * 32768 + wid * 8192;
#pragma unroll
    for (int j = 0; j < 8; j++) {
      int row = srow0 + j * 2;
      int gg = sgs ^ (row & 31);
      async_load16(src + (size_t)row * EDIM + gg * 8, base + j * 1024);
    }
  };

  auto compute = [&](int st, int b) {
    const char* bbase = (const char*)Cs + b * 32768;
    const int cb0 = g * GSIZE + st * 64;
    float ev[4];
#pragma unroll
    for (int u = 0; u < 4; u++) ev[u] = e2p[cb0 + u * 16 + col];
    f32x4 c[3][4] = {};
#pragma unroll
    for (int s = 0; s < 8; s++) {
      bf16x8 bb[4];
#pragma unroll
      for (int u = 0; u < 4; u++) {
        int row = u * 16 + col;
        bb[u] = *(const bf16x8*)(bbase + (row * 32 + ((s * 4 + quad) ^ (row & 31))) * 16);
      }
#pragma unroll
      for (int t = 0; t < 3; t++)
#pragma unroll
        for (int u = 0; u < 4; u++) c[t][u] = mfma16(af[t][s], bb[u], c[t][u]);
    }
#pragma unroll
    for (int u = 0; u < 4; u++) {
      u32 iv = (u32)(st * 4 + u);
#pragma unroll
      for (int t = 0; t < 3; t++)
#pragma unroll
        for (int r = 0; r < 4; r++) {
          u32 du = __float_as_uint(fmaf(c[t][u][r], -2.0f, ev[u]));
          u32 key = (du & 0xFFFFFFC0u) | iv;  // v_and_or_b32
          best[t][r] = key < best[t][r] ? key : best[t][r];  // v_min_u32
        }
    }
  };

  stage_load(0, 0);
  for (int st = 0; st < 16; st++) {
    __syncthreads();
    if (st < 15) stage_load(st + 1, (st + 1) & 1);
    compute(st, st & 1);
  }

  // cross-col reduce on packed keys, carrying winning col
#pragma unroll
  for (int t = 0; t < 3; t++)
#pragma unroll
    for (int r = 0; r < 4; r++) {
      u32 key = best[t][r];
      int cw = col;
#pragma unroll
      for (int off = 1; off < 16; off <<= 1) {
        u32 ok = (u32)__shfl_xor((int)key, off, 64);
        int oc = __shfl_xor(cw, off, 64);
        if (ok < key) { key = ok; cw = oc; }
      }
      if (col == 0) {
        int token = tw + t * 16 + quad * 4 + r;
        pval[token * GROUPS + g] = __uint_as_float(key & 0xFFFFFFC0u);
        // code = g*1024 + stage*64 + u*16 + col == g*1024 + (lid6)*16 + col
        pidx[token * GROUPS + g] = g * GSIZE + (int)(key & 63u) * 16 + cw;
      }
    }
}

// ---------------- gather + per-block loss partial ----------------
__global__ __launch_bounds__(256) void k_gather(const float* __restrict__ cb,
                                                const bf16* __restrict__ zb,
                                                const float* __restrict__ pval,
                                                const int* __restrict__ pidx,
                                                bf16* __restrict__ zqb,
                                                float* __restrict__ lpart) {
  __shared__ float ls[4];
  int wv = threadIdx.x >> 6;
  int token = blockIdx.x * 4 + wv;
  int lane = threadIdx.x & 63;
  float v = 3.4e38f;
  int idx = 0;
  if (lane < 16) {
    v = pval[token * GROUPS + lane];
    idx = pidx[token * GROUPS + lane];
  }
#pragma unroll
  for (int off = 1; off < 16; off <<= 1) {
    float ov = __shfl_xor(v, off, 64);
    int oi = __shfl_xor(idx, off, 64);
    if (ov < v || (ov == v && oi < idx)) { v = ov; idx = oi; }
  }
  idx = __shfl(idx, 0, 64);
  float4 q = ((const float4*)(cb + (size_t)idx * EDIM))[lane];
  bf16x4 zv = *(const bf16x4*)(zb + (size_t)token * EDIM + lane * 4);
  bf16x4 o = {(bf16)q.x, (bf16)q.y, (bf16)q.z, (bf16)q.w};
  *(bf16x4*)(zqb + (size_t)token * EDIM + lane * 4) = o;
  float dx = q.x - (float)zv[0], dy = q.y - (float)zv[1];
  float dz = q.z - (float)zv[2], dw = q.w - (float)zv[3];
  float s = dx * dx + dy * dy + dz * dz + dw * dw;
#pragma unroll
  for (int off = 32; off; off >>= 1) s += __shfl_xor(s, off, 64);
  if (lane == 0) ls[wv] = s;
  __syncthreads();
  if (threadIdx.x == 0) lpart[blockIdx.x] = ls[0] + ls[1] + ls[2] + ls[3];
}

__global__ __launch_bounds__(256) void k_loss(const float* __restrict__ lpart,
                                              float* __restrict__ outl) {
  __shared__ float ls[4];
  float s = 0.f;
  for (int i = threadIdx.x; i < NBLK_GATHER; i += 256) s += lpart[i];
#pragma unroll
  for (int off = 32; off; off >>= 1) s += __shfl_xor(s, off, 64);
  int wv = threadIdx.x >> 6;
  if ((threadIdx.x & 63) == 0) ls[wv] = s;
  __syncthreads();
  if (threadIdx.x == 0) *outl = 1.25f * (ls[0] + ls[1] + ls[2] + ls[3]) / LOSS_DENOM;
}

// ---------------- launch ----------------
extern "C" void kernel_launch(void* const* d_in, const int* in_sizes, int n_in,
                              void* d_out, int out_size, void* d_ws, size_t ws_size,
                              hipStream_t stream) {
  const float* x = (const float*)d_in[0];
  const float* enc_w = (const float*)d_in[1];
  const float* enc_b = (const float*)d_in[2];
  const float* cb = (const float*)d_in[3];
  const float* dec_w = (const float*)d_in[4];
  const float* dec_b = (const float*)d_in[5];
  float* out = (float*)d_out;
  float* out_loss = out + (size_t)N_TOK * SRC;

  char* ws = (char*)d_ws;
  bf16* xb = (bf16*)(ws + 0);              // 18,874,368 B
  bf16* enc_wT = (bf16*)(ws + 18874368);   //    524,288 B
  bf16* dec_wT = (bf16*)(ws + 19398656);   //    524,288 B
  bf16* zb = (bf16*)(ws + 19922944);       //  4,718,592 B
  bf16* cbb = (bf16*)(ws + 24641536);      //  8,388,608 B
  float* e2p = (float*)(ws + 33030144);    //     65,536 B
  float* pval = (float*)(ws + 33095680);   //    589,824 B
  int* pidx = (int*)(ws + 33685504);       //    589,824 B
  bf16* zqb = (bf16*)(ws + 34275328);      //  4,718,592 B
  float* lpart = (float*)(ws + 38993920);  //      9,216 B   (~39 MiB total)

  k_prep<<<14336, 256, 0, stream>>>(x, enc_w, dec_w, cb, xb, enc_wT, dec_wT, cbb, e2p);
  // encoder: z = x @ enc_w + enc_b  (M=9216, K=1024, N=256), bf16 out only
  k_gemm<64><<<dim3(72, 4), 256, 0, stream>>>(xb, enc_wT, enc_b, nullptr, zb, 1024, 256);
  // fused distance + argmin: 768 blocks = exactly 3/CU
  k_argmin<<<dim3(48, GROUPS), 256, 0, stream>>>(zb, cbb, e2p, pval, pidx);
  k_gather<<<NBLK_GATHER, 256, 0, stream>>>(cb, zb, pval, pidx, zqb, lpart);
  // decoder: out = z_q @ dec_w + dec_b  (M=9216, K=256, N=1024)
  k_gemm<128><<<dim3(72, 8), 256, 0, stream>>>(zqb, dec_wT, dec_b, out, nullptr, 256, 1024);
  k_loss<<<1, 256, 0, stream>>>(lpart, out_loss);
}

// Round 6
// 216.451 us; speedup vs baseline: 2.1504x; 1.0655x over previous
//
#include <hip/hip_runtime.h>

typedef __bf16 bf16;
typedef __bf16 bf16x8 __attribute__((ext_vector_type(8)));
typedef float f32x4 __attribute__((ext_vector_type(4)));
typedef unsigned int u32;
typedef long long i64;
typedef i64 i64x2 __attribute__((ext_vector_type(2)));
typedef unsigned char u8;

#define N_TOK 9216
#define SRC 1024
#define EDIM 256
#define NE 16384
#define GROUPS 16
#define GSIZE 1024
#define NBLK_GATHER 2304
#define CB_SCALE 8192.0f
#define NEG_TWO_OVER_SCALE -2.44140625e-4f  // -2/8192
#define LOSS_DENOM 2359296.0f               // 16*576*256

__device__ __forceinline__ void async_load16(const void* g, void* l) {
  __builtin_amdgcn_global_load_lds(
      (__attribute__((address_space(1))) void*)(void*)(const_cast<void*>(g)),
      (__attribute__((address_space(3))) void*)l, 16, 0, 0);
}

__device__ __forceinline__ f32x4 mfma16(bf16x8 a, bf16x8 b, f32x4 c) {
  return __builtin_amdgcn_mfma_f32_16x16x32_bf16(a, b, c, 0, 0, 0);
}
__device__ __forceinline__ f32x4 mfma_fp8(i64 a, i64 b, f32x4 c) {
  return __builtin_amdgcn_mfma_f32_16x16x32_fp8_fp8(a, b, c, 0, 0, 0);
}

// ---------------- prep: weight transposes + fp8 codebook (fragment-major,
// XOR-swizzled granules, pre-scaled x8192) + ||e||^2 + 1 ----------------
// Codebook permuted layout per row (256 B): granule slot g (16B) holds source
// fragment-granule h = g ^ (row&15); granule h covers k = (2*(h&3)+{0,1})*32 +
// (h>>2)*8 + j  (low 8B = even k-step, high 8B = odd) so one LDS b128 read
// feeds two K=32 fp8 MFMA fragments.
__global__ __launch_bounds__(256) void k_prep(const float* __restrict__ enc_w,
                                              const float* __restrict__ dec_w,
                                              const float* __restrict__ cb,
                                              bf16* __restrict__ enc_wT,
                                              bf16* __restrict__ dec_wT,
                                              u32* __restrict__ cbb8,
                                              float* __restrict__ e2p) {
  int b = blockIdx.x;
  if (b < 1024) {
    int id = b * 256 + threadIdx.x;
    {
      int n = id >> 10, k = id & 1023;
      enc_wT[id] = (bf16)enc_w[k * EDIM + n];
    }
    {
      int n = id >> 8, k = id & 255;
      dec_wT[id] = (bf16)dec_w[k * SRC + n];
    }
  } else {
    int row = (b - 1024) * 4 + (threadIdx.x >> 6);
    int lane = threadIdx.x & 63;
    // lane emits permuted bytes p = 4*lane .. 4*lane+3
    int slot = lane >> 2;
    int h = slot ^ (row & 15);
    int bo = (lane & 3) * 4;
    int s = 2 * (h & 3) + (bo >> 3);
    int k0 = s * 32 + (h >> 2) * 8 + (bo & 7);
    float4 v = *(const float4*)(cb + (size_t)row * EDIM + k0);
    int pk = __builtin_amdgcn_cvt_pk_fp8_f32(v.x * CB_SCALE, v.y * CB_SCALE, 0, false);
    pk = __builtin_amdgcn_cvt_pk_fp8_f32(v.z * CB_SCALE, v.w * CB_SCALE, pk, true);
    cbb8[(size_t)row * 64 + lane] = (u32)pk;
    float sq = v.x * v.x + v.y * v.y + v.z * v.z + v.w * v.w;
#pragma unroll
    for (int off = 32; off; off >>= 1) sq += __shfl_xor(sq, off, 64);
    if (lane == 0) e2p[row] = sq + 1.0f;  // +1 keeps packed keys positive
  }
}

// ---------------- 128xBN bf16 MFMA GEMM, double-buffered LDS ----------------
// C = A[M,K] * BT[N,K]^T + bias. 4 waves 2x2; wave tile 64 x (BN/2).
// AF32: A is f32, staged via VGPR + cvt + ds_write (fused cast).
// LDS granule (row, g) stored at slot g ^ (row&3).
template <int BN, bool AF32>
__global__ __launch_bounds__(256) void k_gemm(const void* __restrict__ Ap,
                                              const bf16* __restrict__ BT,
                                              const float* __restrict__ bias,
                                              float* __restrict__ Cf,
                                              u8* __restrict__ C8, int K, int N) {
  __shared__ __align__(16) bf16 As[2][128 * 32];
  __shared__ __align__(16) bf16 Bs[2][BN * 32];
  const int tid = threadIdx.x;
  const int wid = tid >> 6, lane = tid & 63;
  const int col = lane & 15, quad = lane >> 4;
  constexpr int WN = BN / 2, UN = BN / 32;
  const int wm = (wid >> 1) * 64, wn = (wid & 1) * WN;
  const int bm = blockIdx.x * 128, bn = blockIdx.y * BN;
  const bf16* Ab = (const bf16*)Ap;
  const float* Af = (const float*)Ap;
  f32x4 acc[4][UN] = {};

  const int ar0 = tid >> 2, ag0 = tid & 3;  // granule tid
  const int ar1 = ar0 + 64;                 // granule tid+256 (same ag)

  auto stageB = [&](int kc, int bb) {
#pragma unroll
    for (int j = 0; j < BN / 64; j++) {
      int slot = wid * (BN / 64) * 64 + j * 64 + lane;
      int row = slot >> 2;
      int gg = (slot & 3) ^ (row & 3);
      async_load16(BT + (size_t)(bn + row) * K + kc + gg * 8,
                   (char*)&Bs[bb][0] + wid * (BN / 64) * 1024 + j * 1024);
    }
  };
  auto stageA_async = [&](int kc, int bb) {
#pragma unroll
    for (int j = 0; j < 2; j++) {
      int slot = wid * 128 + j * 64 + lane;
      int row = slot >> 2;
      int gg = (slot & 3) ^ (row & 3);
      async_load16(Ab + (size_t)(bm + row) * K + kc + gg * 8,
                   (char*)&As[bb][0] + wid * 2048 + j * 1024);
    }
  };

  float4 p0, p1, p2, p3;
  auto loadA_f32 = [&](int kc) {
    const float* a0 = Af + (size_t)(bm + ar0) * K + kc + ag0 * 8;
    const float* a1 = Af + (size_t)(bm + ar1) * K + kc + ag0 * 8;
    p0 = *(const float4*)a0;
    p1 = *(const float4*)(a0 + 4);
    p2 = *(const float4*)a1;
    p3 = *(const float4*)(a1 + 4);
  };
  auto writeA_f32 = [&](int bb) {
    bf16x8 o0 = {(bf16)p0.x, (bf16)p0.y, (bf16)p0.z, (bf16)p0.w,
                 (bf16)p1.x, (bf16)p1.y, (bf16)p1.z, (bf16)p1.w};
    bf16x8 o1 = {(bf16)p2.x, (bf16)p2.y, (bf16)p2.z, (bf16)p2.w,
                 (bf16)p3.x, (bf16)p3.y, (bf16)p3.z, (bf16)p3.w};
    *(bf16x8*)((char*)&As[bb][0] + (ar0 * 4 + (ag0 ^ (ar0 & 3))) * 16) = o0;
    *(bf16x8*)((char*)&As[bb][0] + (ar1 * 4 + (ag0 ^ (ar1 & 3))) * 16) = o1;
  };

  const int iters = K / 32;
  if (AF32) {
    loadA_f32(0);
    writeA_f32(0);
  } else {
    stageA_async(0, 0);
  }
  stageB(0, 0);

  for (int it = 0; it < iters; it++) {
    int cbuf = it & 1, nbuf = cbuf ^ 1;
    if (AF32 && it + 1 < iters) loadA_f32((it + 1) * 32);  // issue early
    __syncthreads();
    if (it + 1 < iters) {
      if (!AF32) stageA_async((it + 1) * 32, nbuf);
      stageB((it + 1) * 32, nbuf);
    }
    bf16x8 afr[4], bfr[UN];
#pragma unroll
    for (int t = 0; t < 4; t++) {
      int row = wm + t * 16 + col;
      afr[t] = *(const bf16x8*)((const char*)&As[cbuf][0] +
                                (row * 4 + (quad ^ (row & 3))) * 16);
    }
#pragma unroll
    for (int u = 0; u < UN; u++) {
      int row = wn + u * 16 + col;
      bfr[u] = *(const bf16x8*)((const char*)&Bs[cbuf][0] +
                                (row * 4 + (quad ^ (row & 3))) * 16);
    }
#pragma unroll
    for (int t = 0; t < 4; t++)
#pragma unroll
      for (int u = 0; u < UN; u++) acc[t][u] = mfma16(afr[t], bfr[u], acc[t][u]);
    if (AF32 && it + 1 < iters) writeA_f32(nbuf);
  }

#pragma unroll
  for (int u = 0; u < UN; u++) {
    int n = bn + wn + u * 16 + col;
    float bv = bias[n];
#pragma unroll
    for (int t = 0; t < 4; t++) {
#pragma unroll
      for (int r = 0; r < 4; r++) {
        int m = bm + wm + t * 16 + quad * 4 + r;
        float v = acc[t][u][r] + bv;
        if (Cf) Cf[(size_t)m * N + n] = v;
        if (C8) {
          int pk = __builtin_amdgcn_cvt_pk_fp8_f32(v, v, 0, false);
          C8[(size_t)m * N + n] = (u8)(pk & 0xFF);
        }
      }
    }
  }
}

// ---------------- fused fp8 cross-GEMM + argmin v5 ----------------
// Block: 192 tokens x 1024-code group; 4 waves x 48 tokens (af[3][8] fp8 = 48 VGPR).
// Stage = 64 codes x 256 (16 KB fp8), double-buffered (32 KB LDS -> 3 blocks/CU,
// grid 768 = exactly 3/CU resident). One barrier/stage. Packed-key argmin.
__global__ __launch_bounds__(256, 3) void k_argmin(const u8* __restrict__ zb8,
                                                   const u8* __restrict__ cbb8,
                                                   const float* __restrict__ e2p,
                                                   float* __restrict__ pval,
                                                   int* __restrict__ pidx) {
  __shared__ __align__(16) u8 Cs[2 * 16384];
  const int tid = threadIdx.x;
  const int wid = tid >> 6, lane = tid & 63;
  const int col = lane & 15, quad = lane >> 4;
  const int g = blockIdx.y;
  const int tw = blockIdx.x * 192 + wid * 48;

  i64 af[3][8];
#pragma unroll
  for (int t = 0; t < 3; t++)
#pragma unroll
    for (int s = 0; s < 8; s++)
      af[t][s] = *(const i64*)(zb8 + (size_t)(tw + t * 16 + col) * EDIM + s * 32 + quad * 8);

  u32 best[3][4];
#pragma unroll
  for (int t = 0; t < 3; t++)
#pragma unroll
    for (int r = 0; r < 4; r++) best[t][r] = 0xFFFFFFFFu;

  auto stage_load = [&](int st, int bb) {
    const u8* src = cbb8 + (size_t)(g * GSIZE + st * 64) * EDIM;
#pragma unroll
    for (int j = 0; j < 4; j++) {
      async_load16(src + (wid * 256 + j * 64 + lane) * 16,
                   (char*)Cs + bb * 16384 + wid * 4096 + j * 1024);
    }
  };

  auto compute = [&](int st, int bb) {
    const char* bbase = (const char*)Cs + bb * 16384;
    const int cb0 = g * GSIZE + st * 64;
    float ev[4];
#pragma unroll
    for (int u = 0; u < 4; u++) ev[u] = e2p[cb0 + u * 16 + col];
    f32x4 c[3][4] = {};
#pragma unroll
    for (int s2 = 0; s2 < 4; s2++) {
#pragma unroll
      for (int u = 0; u < 4; u++) {
        int row = u * 16 + col;
        i64x2 bb2 = *(const i64x2*)(bbase + row * 256 + (((quad * 4 + s2) ^ col) * 16));
#pragma unroll
        for (int t = 0; t < 3; t++) {
          c[t][u] = mfma_fp8(af[t][2 * s2], bb2.x, c[t][u]);
          c[t][u] = mfma_fp8(af[t][2 * s2 + 1], bb2.y, c[t][u]);
        }
      }
    }
#pragma unroll
    for (int u = 0; u < 4; u++) {
      u32 iv = (u32)(st * 4 + u);
#pragma unroll
      for (int t = 0; t < 3; t++)
#pragma unroll
        for (int r = 0; r < 4; r++) {
          u32 du = __float_as_uint(fmaf(c[t][u][r], NEG_TWO_OVER_SCALE, ev[u]));
          u32 key = (du & 0xFFFFFFC0u) | iv;
          best[t][r] = key < best[t][r] ? key : best[t][r];
        }
    }
  };

  stage_load(0, 0);
  for (int st = 0; st < 16; st++) {
    __syncthreads();
    if (st < 15) stage_load(st + 1, (st + 1) & 1);
    compute(st, st & 1);
  }

#pragma unroll
  for (int t = 0; t < 3; t++)
#pragma unroll
    for (int r = 0; r < 4; r++) {
      u32 key = best[t][r];
      int cw = col;
#pragma unroll
      for (int off = 1; off < 16; off <<= 1) {
        u32 ok = (u32)__shfl_xor((int)key, off, 64);
        int oc = __shfl_xor(cw, off, 64);
        if (ok < key) { key = ok; cw = oc; }
      }
      if (col == 0) {
        int token = tw + t * 16 + quad * 4 + r;
        pval[token * GROUPS + g] = __uint_as_float(key & 0xFFFFFFC0u);
        pidx[token * GROUPS + g] = g * GSIZE + (int)(key & 63u) * 16 + cw;
      }
    }
}

// ---------------- gather + per-block loss partial ----------------
__global__ __launch_bounds__(256) void k_gather(const float* __restrict__ cb,
                                                const u8* __restrict__ zb8,
                                                const float* __restrict__ pval,
                                                const int* __restrict__ pidx,
                                                bf16* __restrict__ zqb,
                                                float* __restrict__ lpart) {
  __shared__ float ls[4];
  int wv = threadIdx.x >> 6;
  int token = blockIdx.x * 4 + wv;
  int lane = threadIdx.x & 63;
  float v = 3.4e38f;
  int idx = 0;
  if (lane < 16) {
    v = pval[token * GROUPS + lane];
    idx = pidx[token * GROUPS + lane];
  }
#pragma unroll
  for (int off = 1; off < 16; off <<= 1) {
    float ov = __shfl_xor(v, off, 64);
    int oi = __shfl_xor(idx, off, 64);
    if (ov < v || (ov == v && oi < idx)) { v = ov; idx = oi; }
  }
  idx = __shfl(idx, 0, 64);
  float4 q = ((const float4*)(cb + (size_t)idx * EDIM))[lane];
  u32 zw = *(const u32*)(zb8 + (size_t)token * EDIM + lane * 4);
  float z0 = __builtin_amdgcn_cvt_f32_fp8(zw, 0);
  float z1 = __builtin_amdgcn_cvt_f32_fp8(zw, 1);
  float z2 = __builtin_amdgcn_cvt_f32_fp8(zw, 2);
  float z3 = __builtin_amdgcn_cvt_f32_fp8(zw, 3);
  bf16* zq = zqb + (size_t)token * EDIM + lane * 4;
  zq[0] = (bf16)q.x;
  zq[1] = (bf16)q.y;
  zq[2] = (bf16)q.z;
  zq[3] = (bf16)q.w;
  float dx = q.x - z0, dy = q.y - z1, dz = q.z - z2, dw = q.w - z3;
  float s = dx * dx + dy * dy + dz * dz + dw * dw;
#pragma unroll
  for (int off = 32; off; off >>= 1) s += __shfl_xor(s, off, 64);
  if (lane == 0) ls[wv] = s;
  __syncthreads();
  if (threadIdx.x == 0) lpart[blockIdx.x] = ls[0] + ls[1] + ls[2] + ls[3];
}

__global__ __launch_bounds__(256) void k_loss(const float* __restrict__ lpart,
                                              float* __restrict__ outl) {
  __shared__ float ls[4];
  float s = 0.f;
  for (int i = threadIdx.x; i < NBLK_GATHER; i += 256) s += lpart[i];
#pragma unroll
  for (int off = 32; off; off >>= 1) s += __shfl_xor(s, off, 64);
  int wv = threadIdx.x >> 6;
  if ((threadIdx.x & 63) == 0) ls[wv] = s;
  __syncthreads();
  if (threadIdx.x == 0) *outl = 1.25f * (ls[0] + ls[1] + ls[2] + ls[3]) / LOSS_DENOM;
}

// ---------------- launch ----------------
extern "C" void kernel_launch(void* const* d_in, const int* in_sizes, int n_in,
                              void* d_out, int out_size, void* d_ws, size_t ws_size,
                              hipStream_t stream) {
  const float* x = (const float*)d_in[0];
  const float* enc_w = (const float*)d_in[1];
  const float* enc_b = (const float*)d_in[2];
  const float* cb = (const float*)d_in[3];
  const float* dec_w = (const float*)d_in[4];
  const float* dec_b = (const float*)d_in[5];
  float* out = (float*)d_out;
  float* out_loss = out + (size_t)N_TOK * SRC;

  char* ws = (char*)d_ws;
  bf16* enc_wT = (bf16*)(ws + 0);          //   524,288 B
  bf16* dec_wT = (bf16*)(ws + 524288);     //   524,288 B
  u8* zb8 = (u8*)(ws + 1048576);           // 2,359,296 B
  u32* cbb8 = (u32*)(ws + 3407872);        // 4,194,304 B
  float* e2p = (float*)(ws + 7602176);     //    65,536 B
  float* pval = (float*)(ws + 7667712);    //   589,824 B
  int* pidx = (int*)(ws + 8257536);        //   589,824 B
  bf16* zqb = (bf16*)(ws + 8847360);       // 4,718,592 B
  float* lpart = (float*)(ws + 13565952);  //     9,216 B   (~13.6 MiB)

  // weights transpose + fp8 codebook prep
  k_prep<<<5120, 256, 0, stream>>>(enc_w, dec_w, cb, enc_wT, dec_wT, cbb8, e2p);
  // encoder: z = x @ enc_w + enc_b (M=9216,K=1024,N=256), fused f32->bf16 staging,
  // fp8 z output
  k_gemm<64, true><<<dim3(72, 4), 256, 0, stream>>>(x, enc_wT, enc_b, nullptr, zb8,
                                                    1024, 256);
  // fused fp8 distance + argmin: 768 blocks = exactly 3/CU
  k_argmin<<<dim3(48, GROUPS), 256, 0, stream>>>(zb8, (const u8*)cbb8, e2p, pval, pidx);
  k_gather<<<NBLK_GATHER, 256, 0, stream>>>(cb, zb8, pval, pidx, zqb, lpart);
  // decoder: out = z_q @ dec_w + dec_b (M=9216,K=256,N=1024)
  k_gemm<128, false><<<dim3(72, 8), 256, 0, stream>>>(zqb, dec_wT, dec_b, out, nullptr,
                                                      256, 1024);
  k_loss<<<1, 256, 0, stream>>>(lpart, out_loss);
}

// Round 7
// 199.890 us; speedup vs baseline: 2.3286x; 1.0829x over previous
//
#include <hip/hip_runtime.h>

typedef __bf16 bf16;
typedef __bf16 bf16x8 __attribute__((ext_vector_type(8)));
typedef float f32x4 __attribute__((ext_vector_type(4)));
typedef int i32x8 __attribute__((ext_vector_type(8)));
typedef unsigned int u32;
typedef unsigned char u8;

#define N_TOK 9216
#define SRC 1024
#define EDIM 256
#define NE 16384
#define GROUPS 16
#define GSIZE 1024
#define NBLK_GATHER 2304
#define NEG_CB_SCALE -8192.0f
#define E2_SCALE 4096.0f
#define LOSS_DENOM 2359296.0f  // 16*576*256

__device__ __forceinline__ void async_load16(const void* g, void* l) {
  __builtin_amdgcn_global_load_lds(
      (__attribute__((address_space(1))) void*)(void*)(const_cast<void*>(g)),
      (__attribute__((address_space(3))) void*)l, 16, 0, 0);
}

__device__ __forceinline__ f32x4 mfma16(bf16x8 a, bf16x8 b, f32x4 c) {
  return __builtin_amdgcn_mfma_f32_16x16x32_bf16(a, b, c, 0, 0, 0);
}
// MX-scaled fp8 K=128; scale bytes 0x7F = 2^0 = 1.0; cbsz/blgp 0 = fp8 e4m3
__device__ __forceinline__ f32x4 mfma_mx(i32x8 a, i32x8 b, f32x4 c) {
  return __builtin_amdgcn_mfma_scale_f32_16x16x128_f8f6f4(
      a, b, c, 0, 0, 0, 0x7F7F7F7F, 0, 0x7F7F7F7F);
}

// ---------------- prep: weight transposes + fp8 codebook ----------------
// Codebook row r (256 B, 16 granules of 16 B): stored slot s holds source
// granule h = (s&8) | ((s&7) ^ (r&7)), values scaled by -8192 (negated so the
// distance epilogue is a single add). K=128 fragment for (quad,m) reads stored
// slots m*8 + ((2q)^ (r&7)) and m*8 + ((2q+1)^(r&7)) -> source granules
// 8m+2q, 8m+2q+1 = k range m*128 + q*32 .. +31. e2s = 4096*(||e||^2 + 1).
__global__ __launch_bounds__(256) void k_prep(const float* __restrict__ enc_w,
                                              const float* __restrict__ dec_w,
                                              const float* __restrict__ cb,
                                              bf16* __restrict__ enc_wT,
                                              bf16* __restrict__ dec_wT,
                                              u32* __restrict__ cbb8,
                                              float* __restrict__ e2s) {
  int b = blockIdx.x;
  if (b < 1024) {
    int id = b * 256 + threadIdx.x;
    {
      int n = id >> 10, k = id & 1023;
      enc_wT[id] = (bf16)enc_w[k * EDIM + n];
    }
    {
      int n = id >> 8, k = id & 255;
      dec_wT[id] = (bf16)dec_w[k * SRC + n];
    }
  } else {
    int row = (b - 1024) * 4 + (threadIdx.x >> 6);
    int lane = threadIdx.x & 63;
    int slot = lane >> 2;
    int h = (slot & 8) | ((slot & 7) ^ (row & 7));
    int k0 = h * 16 + (lane & 3) * 4;
    float4 v = *(const float4*)(cb + (size_t)row * EDIM + k0);
    int pk = __builtin_amdgcn_cvt_pk_fp8_f32(v.x * NEG_CB_SCALE, v.y * NEG_CB_SCALE, 0, false);
    pk = __builtin_amdgcn_cvt_pk_fp8_f32(v.z * NEG_CB_SCALE, v.w * NEG_CB_SCALE, pk, true);
    cbb8[(size_t)row * 64 + lane] = (u32)pk;
    float sq = v.x * v.x + v.y * v.y + v.z * v.z + v.w * v.w;
#pragma unroll
    for (int off = 32; off; off >>= 1) sq += __shfl_xor(sq, off, 64);
    if (lane == 0) e2s[row] = E2_SCALE * (sq + 1.0f);
  }
}

// ---------------- encoder GEMM: 64x128 tile, fused f32->bf16, fp8 out -------
// z = x @ enc_wT^T + enc_b. grid (144,2). 4 waves 2x2, wave tile 32x64.
__global__ __launch_bounds__(256) void k_enc(const float* __restrict__ x,
                                             const bf16* __restrict__ wT,
                                             const float* __restrict__ bias,
                                             u8* __restrict__ z8) {
  __shared__ __align__(16) bf16 As[2][64 * 32];
  __shared__ __align__(16) bf16 Bs[2][128 * 32];
  const int tid = threadIdx.x;
  const int wid = tid >> 6, lane = tid & 63;
  const int col = lane & 15, quad = lane >> 4;
  const int wm = (wid >> 1) * 32, wn = (wid & 1) * 64;
  const int bm = blockIdx.x * 64, bn = blockIdx.y * 128;
  f32x4 acc[2][4] = {};
  const int arow = tid >> 2, ags = tid & 3;  // A: 256 bf16 granules, 1/thread

  float4 q0, q1;
  auto loadA = [&](int kc) {
    const float* p = x + (size_t)(bm + arow) * SRC + kc + ags * 8;
    q0 = *(const float4*)p;
    q1 = *(const float4*)(p + 4);
  };
  auto writeA = [&](int bb) {
    bf16x8 o = {(bf16)q0.x, (bf16)q0.y, (bf16)q0.z, (bf16)q0.w,
                (bf16)q1.x, (bf16)q1.y, (bf16)q1.z, (bf16)q1.w};
    *(bf16x8*)((char*)&As[bb][0] + (arow * 4 + (ags ^ (arow & 3))) * 16) = o;
  };
  auto stageB = [&](int kc, int bb) {
#pragma unroll
    for (int j = 0; j < 2; j++) {
      int slot = wid * 128 + j * 64 + lane;
      int row = slot >> 2;
      int gg = (slot & 3) ^ (row & 3);
      async_load16(wT + (size_t)(bn + row) * SRC + kc + gg * 8,
                   (char*)&Bs[bb][0] + wid * 2048 + j * 1024);
    }
  };

  loadA(0);
  writeA(0);
  stageB(0, 0);
  for (int it = 0; it < 32; it++) {
    int cbuf = it & 1, nbuf = cbuf ^ 1;
    if (it < 31) loadA((it + 1) * 32);
    __syncthreads();
    if (it < 31) stageB((it + 1) * 32, nbuf);
    bf16x8 afr[2], bfr[4];
#pragma unroll
    for (int t = 0; t < 2; t++) {
      int row = wm + t * 16 + col;
      afr[t] = *(const bf16x8*)((const char*)&As[cbuf][0] +
                                (row * 4 + (quad ^ (row & 3))) * 16);
    }
#pragma unroll
    for (int u = 0; u < 4; u++) {
      int row = wn + u * 16 + col;
      bfr[u] = *(const bf16x8*)((const char*)&Bs[cbuf][0] +
                                (row * 4 + (quad ^ (row & 3))) * 16);
    }
#pragma unroll
    for (int t = 0; t < 2; t++)
#pragma unroll
      for (int u = 0; u < 4; u++) acc[t][u] = mfma16(afr[t], bfr[u], acc[t][u]);
    if (it < 31) writeA(nbuf);
  }
#pragma unroll
  for (int u = 0; u < 4; u++) {
    int n = bn + wn + u * 16 + col;
    float bv = bias[n];
#pragma unroll
    for (int t = 0; t < 2; t++)
#pragma unroll
      for (int r = 0; r < 4; r++) {
        int m = bm + wm + t * 16 + quad * 4 + r;
        float v = acc[t][u][r] + bv;
        int pk = __builtin_amdgcn_cvt_pk_fp8_f32(v, v, 0, false);
        z8[(size_t)m * EDIM + n] = (u8)(pk & 0xFF);
      }
  }
}

// ---------------- fused MX-fp8 cross-GEMM + argmin v6 (K=128) ----------------
// Block: 192 tokens x 1024-code group; 4 waves x 48 tokens (af[3][2] v8i32 = 48 VGPR).
// Stage = 64 codes x 256 B (16 KB), double-buffered (32 KB LDS), grid 768 = 3/CU.
// d*4096 = e2s + acc (codebook negated); packed-key argmin (low 6 bits = st*4+u).
__global__ __launch_bounds__(256, 3) void k_argmin(const u8* __restrict__ zb8,
                                                   const u8* __restrict__ cbb8,
                                                   const float* __restrict__ e2s,
                                                   float* __restrict__ pval,
                                                   int* __restrict__ pidx) {
  __shared__ __align__(16) u8 Cs[2 * 16384];
  const int tid = threadIdx.x;
  const int wid = tid >> 6, lane = tid & 63;
  const int col = lane & 15, quad = lane >> 4;
  const int g = blockIdx.y;
  const int tw = blockIdx.x * 192 + wid * 48;

  i32x8 af[3][2];
#pragma unroll
  for (int t = 0; t < 3; t++)
#pragma unroll
    for (int m = 0; m < 2; m++) {
      const u8* p = zb8 + (size_t)(tw + t * 16 + col) * EDIM + m * 128 + quad * 32;
      int4 lo = *(const int4*)p;
      int4 hi = *(const int4*)(p + 16);
      af[t][m] = (i32x8){lo.x, lo.y, lo.z, lo.w, hi.x, hi.y, hi.z, hi.w};
    }

  u32 best[3][4];
#pragma unroll
  for (int t = 0; t < 3; t++)
#pragma unroll
    for (int r = 0; r < 4; r++) best[t][r] = 0xFFFFFFFFu;

  auto stage_load = [&](int st, int bb) {
    const u8* src = cbb8 + (size_t)(g * GSIZE + st * 64) * EDIM;
#pragma unroll
    for (int j = 0; j < 4; j++) {
      async_load16(src + (wid * 256 + j * 64 + lane) * 16,
                   (char*)Cs + bb * 16384 + wid * 4096 + j * 1024);
    }
  };

  auto compute = [&](int st, int bb) {
    const char* bbase = (const char*)Cs + bb * 16384;
    const int cb0 = g * GSIZE + st * 64;
    float ev[4];
#pragma unroll
    for (int u = 0; u < 4; u++) ev[u] = e2s[cb0 + u * 16 + col];
    f32x4 c[3][4] = {};
    const int r7 = col & 7;
#pragma unroll
    for (int m = 0; m < 2; m++) {
#pragma unroll
      for (int u = 0; u < 4; u++) {
        int row = u * 16 + col;
        int s0 = m * 8 + ((2 * quad) ^ r7);
        int s1 = m * 8 + ((2 * quad + 1) ^ r7);
        int4 b0 = *(const int4*)(bbase + row * 256 + s0 * 16);
        int4 b1 = *(const int4*)(bbase + row * 256 + s1 * 16);
        i32x8 bfr = (i32x8){b0.x, b0.y, b0.z, b0.w, b1.x, b1.y, b1.z, b1.w};
#pragma unroll
        for (int t = 0; t < 3; t++) c[t][u] = mfma_mx(af[t][m], bfr, c[t][u]);
      }
    }
#pragma unroll
    for (int u = 0; u < 4; u++) {
      u32 iv = (u32)(st * 4 + u);
#pragma unroll
      for (int t = 0; t < 3; t++)
#pragma unroll
        for (int r = 0; r < 4; r++) {
          u32 du = __float_as_uint(c[t][u][r] + ev[u]);
          u32 key = (du & 0xFFFFFFC0u) | iv;
          best[t][r] = key < best[t][r] ? key : best[t][r];
        }
    }
  };

  stage_load(0, 0);
  for (int st = 0; st < 16; st++) {
    __syncthreads();
    if (st < 15) stage_load(st + 1, (st + 1) & 1);
    compute(st, st & 1);
  }

#pragma unroll
  for (int t = 0; t < 3; t++)
#pragma unroll
    for (int r = 0; r < 4; r++) {
      u32 key = best[t][r];
      int cw = col;
#pragma unroll
      for (int off = 1; off < 16; off <<= 1) {
        u32 ok = (u32)__shfl_xor((int)key, off, 64);
        int oc = __shfl_xor(cw, off, 64);
        if (ok < key) { key = ok; cw = oc; }
      }
      if (col == 0) {
        int token = tw + t * 16 + quad * 4 + r;
        pval[token * GROUPS + g] = __uint_as_float(key & 0xFFFFFFC0u);
        pidx[token * GROUPS + g] = g * GSIZE + (int)(key & 63u) * 16 + cw;
      }
    }
}

// ---------------- gather + per-block loss partial ----------------
__global__ __launch_bounds__(256) void k_gather(const float* __restrict__ cb,
                                                const u8* __restrict__ zb8,
                                                const float* __restrict__ pval,
                                                const int* __restrict__ pidx,
                                                bf16* __restrict__ zqb,
                                                float* __restrict__ lpart) {
  __shared__ float ls[4];
  int wv = threadIdx.x >> 6;
  int token = blockIdx.x * 4 + wv;
  int lane = threadIdx.x & 63;
  float v = 3.4e38f;
  int idx = 0;
  if (lane < 16) {
    v = pval[token * GROUPS + lane];
    idx = pidx[token * GROUPS + lane];
  }
#pragma unroll
  for (int off = 1; off < 16; off <<= 1) {
    float ov = __shfl_xor(v, off, 64);
    int oi = __shfl_xor(idx, off, 64);
    if (ov < v || (ov == v && oi < idx)) { v = ov; idx = oi; }
  }
  idx = __shfl(idx, 0, 64);
  float4 q = ((const float4*)(cb + (size_t)idx * EDIM))[lane];
  u32 zw = *(const u32*)(zb8 + (size_t)token * EDIM + lane * 4);
  float z0 = __builtin_amdgcn_cvt_f32_fp8(zw, 0);
  float z1 = __builtin_amdgcn_cvt_f32_fp8(zw, 1);
  float z2 = __builtin_amdgcn_cvt_f32_fp8(zw, 2);
  float z3 = __builtin_amdgcn_cvt_f32_fp8(zw, 3);
  bf16* zq = zqb + (size_t)token * EDIM + lane * 4;
  zq[0] = (bf16)q.x;
  zq[1] = (bf16)q.y;
  zq[2] = (bf16)q.z;
  zq[3] = (bf16)q.w;
  float dx = q.x - z0, dy = q.y - z1, dz = q.z - z2, dw = q.w - z3;
  float s = dx * dx + dy * dy + dz * dz + dw * dw;
#pragma unroll
  for (int off = 32; off; off >>= 1) s += __shfl_xor(s, off, 64);
  if (lane == 0) ls[wv] = s;
  __syncthreads();
  if (threadIdx.x == 0) lpart[blockIdx.x] = ls[0] + ls[1] + ls[2] + ls[3];
}

// ---------------- decoder GEMM: 64x256 tile, f32 out + bias ----------------
// out = zqb @ dec_wT^T + dec_b. grid (144,4). 4 waves 2x2, wave tile 32x128.
__global__ __launch_bounds__(256) void k_dec(const bf16* __restrict__ A,
                                             const bf16* __restrict__ wT,
                                             const float* __restrict__ bias,
                                             float* __restrict__ out) {
  __shared__ __align__(16) bf16 As[2][64 * 32];
  __shared__ __align__(16) bf16 Bs[2][256 * 32];
  const int tid = threadIdx.x;
  const int wid = tid >> 6, lane = tid & 63;
  const int col = lane & 15, quad = lane >> 4;
  const int wm = (wid >> 1) * 32, wn = (wid & 1) * 128;
  const int bm = blockIdx.x * 64, bn = blockIdx.y * 256;
  f32x4 acc[2][8] = {};

  auto stageA = [&](int kc, int bb) {
    int slot = wid * 64 + lane;
    int row = slot >> 2;
    int gg = (slot & 3) ^ (row & 3);
    async_load16(A + (size_t)(bm + row) * EDIM + kc + gg * 8,
                 (char*)&As[bb][0] + wid * 1024);
  };
  auto stageB = [&](int kc, int bb) {
#pragma unroll
    for (int j = 0; j < 4; j++) {
      int slot = wid * 256 + j * 64 + lane;
      int row = slot >> 2;
      int gg = (slot & 3) ^ (row & 3);
      async_load16(wT + (size_t)(bn + row) * EDIM + kc + gg * 8,
                   (char*)&Bs[bb][0] + wid * 4096 + j * 1024);
    }
  };

  stageA(0, 0);
  stageB(0, 0);
  for (int it = 0; it < 8; it++) {
    int cbuf = it & 1, nbuf = cbuf ^ 1;
    __syncthreads();
    if (it < 7) {
      stageA((it + 1) * 32, nbuf);
      stageB((it + 1) * 32, nbuf);
    }
    bf16x8 afr[2], bfr[8];
#pragma unroll
    for (int t = 0; t < 2; t++) {
      int row = wm + t * 16 + col;
      afr[t] = *(const bf16x8*)((const char*)&As[cbuf][0] +
                                (row * 4 + (quad ^ (row & 3))) * 16);
    }
#pragma unroll
    for (int u = 0; u < 8; u++) {
      int row = wn + u * 16 + col;
      bfr[u] = *(const bf16x8*)((const char*)&Bs[cbuf][0] +
                                (row * 4 + (quad ^ (row & 3))) * 16);
    }
#pragma unroll
    for (int t = 0; t < 2; t++)
#pragma unroll
      for (int u = 0; u < 8; u++) acc[t][u] = mfma16(afr[t], bfr[u], acc[t][u]);
  }
#pragma unroll
  for (int u = 0; u < 8; u++) {
    int n = bn + wn + u * 16 + col;
    float bv = bias[n];
#pragma unroll
    for (int t = 0; t < 2; t++)
#pragma unroll
      for (int r = 0; r < 4; r++) {
        int m = bm + wm + t * 16 + quad * 4 + r;
        out[(size_t)m * SRC + n] = acc[t][u][r] + bv;
      }
  }
}

__global__ __launch_bounds__(256) void k_loss(const float* __restrict__ lpart,
                                              float* __restrict__ outl) {
  __shared__ float ls[4];
  float s = 0.f;
  for (int i = threadIdx.x; i < NBLK_GATHER; i += 256) s += lpart[i];
#pragma unroll
  for (int off = 32; off; off >>= 1) s += __shfl_xor(s, off, 64);
  int wv = threadIdx.x >> 6;
  if ((threadIdx.x & 63) == 0) ls[wv] = s;
  __syncthreads();
  if (threadIdx.x == 0) *outl = 1.25f * (ls[0] + ls[1] + ls[2] + ls[3]) / LOSS_DENOM;
}

// ---------------- launch ----------------
extern "C" void kernel_launch(void* const* d_in, const int* in_sizes, int n_in,
                              void* d_out, int out_size, void* d_ws, size_t ws_size,
                              hipStream_t stream) {
  const float* x = (const float*)d_in[0];
  const float* enc_w = (const float*)d_in[1];
  const float* enc_b = (const float*)d_in[2];
  const float* cb = (const float*)d_in[3];
  const float* dec_w = (const float*)d_in[4];
  const float* dec_b = (const float*)d_in[5];
  float* out = (float*)d_out;
  float* out_loss = out + (size_t)N_TOK * SRC;

  char* ws = (char*)d_ws;
  bf16* enc_wT = (bf16*)(ws + 0);          //   524,288 B
  bf16* dec_wT = (bf16*)(ws + 524288);     //   524,288 B
  u8* zb8 = (u8*)(ws + 1048576);           // 2,359,296 B
  u32* cbb8 = (u32*)(ws + 3407872);        // 4,194,304 B
  float* e2s = (float*)(ws + 7602176);     //    65,536 B
  float* pval = (float*)(ws + 7667712);    //   589,824 B
  int* pidx = (int*)(ws + 8257536);        //   589,824 B
  bf16* zqb = (bf16*)(ws + 8847360);       // 4,718,592 B
  float* lpart = (float*)(ws + 13565952);  //     9,216 B   (~13.6 MiB)

  k_prep<<<5120, 256, 0, stream>>>(enc_w, dec_w, cb, enc_wT, dec_wT, cbb8, e2s);
  // encoder: 64x128 tiles, grid 288, x f32 read only 2x
  k_enc<<<dim3(144, 2), 256, 0, stream>>>(x, enc_wT, enc_b, zb8);
  // fused MX-fp8 K=128 distance + argmin: 768 blocks = exactly 3/CU
  k_argmin<<<dim3(48, GROUPS), 256, 0, stream>>>(zb8, (const u8*)cbb8, e2s, pval, pidx);
  k_gather<<<NBLK_GATHER, 256, 0, stream>>>(cb, zb8, pval, pidx, zqb, lpart);
  // decoder: 64x256 tiles, grid 576, zqb read only 4x
  k_dec<<<dim3(144, 4), 256, 0, stream>>>(zqb, dec_wT, dec_b, out);
  k_loss<<<1, 256, 0, stream>>>(lpart, out_loss);
}

// Round 8
// 189.473 us; speedup vs baseline: 2.4566x; 1.0550x over previous
//
#include <hip/hip_runtime.h>

typedef __bf16 bf16;
typedef __bf16 bf16x8 __attribute__((ext_vector_type(8)));
typedef float f32x4 __attribute__((ext_vector_type(4)));
typedef int i32x8 __attribute__((ext_vector_type(8)));
typedef unsigned int u32;
typedef unsigned char u8;

#define N_TOK 9216
#define SRC 1024
#define EDIM 256
#define NE 16384
#define GROUPS 16
#define GSIZE 1024
#define NBLK_LOSS 144
#define NEG_CB_SCALE -8192.0f
#define E2_SCALE 4096.0f
#define LOSS_DENOM 2359296.0f  // 16*576*256

__device__ __forceinline__ void async_load16(const void* g, void* l) {
  __builtin_amdgcn_global_load_lds(
      (__attribute__((address_space(1))) void*)(void*)(const_cast<void*>(g)),
      (__attribute__((address_space(3))) void*)l, 16, 0, 0);
}

__device__ __forceinline__ f32x4 mfma16(bf16x8 a, bf16x8 b, f32x4 c) {
  return __builtin_amdgcn_mfma_f32_16x16x32_bf16(a, b, c, 0, 0, 0);
}
// MX-scaled fp8 K=128; scale bytes 0x7F = 2^0 = 1.0; cbsz/blgp 0 = fp8 e4m3
__device__ __forceinline__ f32x4 mfma_mx(i32x8 a, i32x8 b, f32x4 c) {
  return __builtin_amdgcn_mfma_scale_f32_16x16x128_f8f6f4(
      a, b, c, 0, 0, 0, 0x7F7F7F7F, 0, 0x7F7F7F7F);
}

// ---------------- prep: coalesced 64x64 LDS transposes + fp8 codebook -------
// b<64: enc_w [1024,256] -> enc_wT [256,1024]; b<128: dec_w [256,1024] ->
// dec_wT [1024,256]; else codebook (negated fp8, fragment-major swizzle) + e2s.
__global__ __launch_bounds__(256) void k_prep(const float* __restrict__ enc_w,
                                              const float* __restrict__ dec_w,
                                              const float* __restrict__ cb,
                                              bf16* __restrict__ enc_wT,
                                              bf16* __restrict__ dec_wT,
                                              u32* __restrict__ cbb8,
                                              float* __restrict__ e2s) {
  int b = blockIdx.x;
  if (b < 128) {
    __shared__ float T[64][65];
    const float* In;
    bf16* Out;
    int R, C, ti, tj;
    if (b < 64) {  // enc: In 1024x256, tiles 16(k) x 4(n)
      In = enc_w; Out = enc_wT; R = 1024; C = 256;
      ti = b & 15; tj = b >> 4;
    } else {       // dec: In 256x1024, tiles 4(k) x 16(n)
      int t2 = b - 64;
      In = dec_w; Out = dec_wT; R = 256; C = 1024;
      ti = t2 & 3; tj = t2 >> 2;
    }
    int c0 = threadIdx.x & 63, r0 = threadIdx.x >> 6;
#pragma unroll
    for (int i = 0; i < 16; i++) {
      int rr = r0 + i * 4;
      T[rr][c0] = In[(size_t)(ti * 64 + rr) * C + tj * 64 + c0];
    }
    __syncthreads();
#pragma unroll
    for (int i = 0; i < 16; i++) {
      int rr = r0 + i * 4;
      Out[(size_t)(tj * 64 + rr) * R + ti * 64 + c0] = (bf16)T[c0][rr];
    }
  } else {
    // codebook row r: stored slot s holds source granule h=(s&8)|((s&7)^(r&7)),
    // scaled by -8192 (negated -> distance epilogue is the MFMA acc itself).
    int row = (b - 128) * 4 + (threadIdx.x >> 6);
    int lane = threadIdx.x & 63;
    int slot = lane >> 2;
    int h = (slot & 8) | ((slot & 7) ^ (row & 7));
    int k0 = h * 16 + (lane & 3) * 4;
    float4 v = *(const float4*)(cb + (size_t)row * EDIM + k0);
    int pk = __builtin_amdgcn_cvt_pk_fp8_f32(v.x * NEG_CB_SCALE, v.y * NEG_CB_SCALE, 0, false);
    pk = __builtin_amdgcn_cvt_pk_fp8_f32(v.z * NEG_CB_SCALE, v.w * NEG_CB_SCALE, pk, true);
    cbb8[(size_t)row * 64 + lane] = (u32)pk;
    float sq = v.x * v.x + v.y * v.y + v.z * v.z + v.w * v.w;
#pragma unroll
    for (int off = 32; off; off >>= 1) sq += __shfl_xor(sq, off, 64);
    if (lane == 0) e2s[row] = E2_SCALE * (sq + 1.0f);
  }
}

// ---------------- encoder GEMM: 64x64 tile, fused f32->bf16, fp8 out --------
// z = x @ enc_wT^T + enc_b. grid (144,4). 4 waves 2x2, wave tile 32x32.
// f32 A-loads issued AFTER the barrier so barriers drain only old async loads.
__global__ __launch_bounds__(256) void k_enc(const float* __restrict__ x,
                                             const bf16* __restrict__ wT,
                                             const float* __restrict__ bias,
                                             u8* __restrict__ z8) {
  __shared__ __align__(16) bf16 As[2][64 * 32];
  __shared__ __align__(16) bf16 Bs[2][64 * 32];
  const int tid = threadIdx.x;
  const int wid = tid >> 6, lane = tid & 63;
  const int col = lane & 15, quad = lane >> 4;
  const int wm = (wid >> 1) * 32, wn = (wid & 1) * 32;
  const int bm = blockIdx.x * 64, bn = blockIdx.y * 64;
  f32x4 acc[2][2] = {};
  const int arow = tid >> 2, ags = tid & 3;

  float4 q0, q1;
  auto loadA = [&](int kc) {
    const float* p = x + (size_t)(bm + arow) * SRC + kc + ags * 8;
    q0 = *(const float4*)p;
    q1 = *(const float4*)(p + 4);
  };
  auto writeA = [&](int bb) {
    bf16x8 o = {(bf16)q0.x, (bf16)q0.y, (bf16)q0.z, (bf16)q0.w,
                (bf16)q1.x, (bf16)q1.y, (bf16)q1.z, (bf16)q1.w};
    *(bf16x8*)((char*)&As[bb][0] + (arow * 4 + (ags ^ (arow & 3))) * 16) = o;
  };
  auto stageB = [&](int kc, int bb) {
    int row = tid >> 2;
    int gg = (tid & 3) ^ (row & 3);
    async_load16(wT + (size_t)(bn + row) * SRC + kc + gg * 8,
                 (char*)&Bs[bb][0] + wid * 1024);
  };

  loadA(0);
  writeA(0);
  stageB(0, 0);
  for (int it = 0; it < 32; it++) {
    int cbuf = it & 1, nbuf = cbuf ^ 1;
    __syncthreads();
    if (it < 31) {
      loadA((it + 1) * 32);
      stageB((it + 1) * 32, nbuf);
    }
    bf16x8 afr[2], bfr[2];
#pragma unroll
    for (int t = 0; t < 2; t++) {
      int row = wm + t * 16 + col;
      afr[t] = *(const bf16x8*)((const char*)&As[cbuf][0] +
                                (row * 4 + (quad ^ (row & 3))) * 16);
    }
#pragma unroll
    for (int u = 0; u < 2; u++) {
      int row = wn + u * 16 + col;
      bfr[u] = *(const bf16x8*)((const char*)&Bs[cbuf][0] +
                                (row * 4 + (quad ^ (row & 3))) * 16);
    }
#pragma unroll
    for (int t = 0; t < 2; t++)
#pragma unroll
      for (int u = 0; u < 2; u++) acc[t][u] = mfma16(afr[t], bfr[u], acc[t][u]);
    if (it < 31) writeA(nbuf);
  }
#pragma unroll
  for (int u = 0; u < 2; u++) {
    int n = bn + wn + u * 16 + col;
    float bv = bias[n];
#pragma unroll
    for (int t = 0; t < 2; t++)
#pragma unroll
      for (int r = 0; r < 4; r++) {
        int m = bm + wm + t * 16 + quad * 4 + r;
        float v = acc[t][u][r] + bv;
        int pk = __builtin_amdgcn_cvt_pk_fp8_f32(v, v, 0, false);
        z8[(size_t)m * EDIM + n] = (u8)(pk & 0xFF);
      }
  }
}

// ---------------- fused MX-fp8 cross-GEMM + argmin v7 ----------------
// Block: 192 tokens x 1024-code group; 4 waves x 48 tokens. Stage = 64 codes
// (16 KB), double-buffered; e2s in LDS (no globals in K-loop -> no vmcnt
// serialization); ev folded into MFMA accumulator init; 2-op key epilogue.
__global__ __launch_bounds__(256, 3) void k_argmin(const u8* __restrict__ zb8,
                                                   const u8* __restrict__ cbb8,
                                                   const float* __restrict__ e2s,
                                                   float* __restrict__ pval,
                                                   int* __restrict__ pidx) {
  __shared__ __align__(16) u8 Cs[2 * 16384];
  __shared__ __align__(16) float Es[1024];
  const int tid = threadIdx.x;
  const int wid = tid >> 6, lane = tid & 63;
  const int col = lane & 15, quad = lane >> 4;
  const int g = blockIdx.y;
  const int tw = blockIdx.x * 192 + wid * 48;

  // e2s for this group -> LDS (one async instr per thread)
  async_load16((const u8*)(e2s + g * GSIZE) + (size_t)tid * 16,
               (char*)Es + wid * 1024);

  i32x8 af[3][2];
#pragma unroll
  for (int t = 0; t < 3; t++)
#pragma unroll
    for (int m = 0; m < 2; m++) {
      const u8* p = zb8 + (size_t)(tw + t * 16 + col) * EDIM + m * 128 + quad * 32;
      int4 lo = *(const int4*)p;
      int4 hi = *(const int4*)(p + 16);
      af[t][m] = (i32x8){lo.x, lo.y, lo.z, lo.w, hi.x, hi.y, hi.z, hi.w};
    }

  u32 best[3][4];
#pragma unroll
  for (int t = 0; t < 3; t++)
#pragma unroll
    for (int r = 0; r < 4; r++) best[t][r] = 0xFFFFFFFFu;

  auto stage_load = [&](int st, int bb) {
    const u8* src = cbb8 + (size_t)(g * GSIZE + st * 64) * EDIM;
#pragma unroll
    for (int j = 0; j < 4; j++) {
      async_load16(src + (wid * 256 + j * 64 + lane) * 16,
                   (char*)Cs + bb * 16384 + wid * 4096 + j * 1024);
    }
  };

  auto compute = [&](int st, int bb) {
    const char* bbase = (const char*)Cs + bb * 16384;
    float ev[4];
#pragma unroll
    for (int u = 0; u < 4; u++) ev[u] = Es[st * 64 + u * 16 + col];
    f32x4 c[3][4];
#pragma unroll
    for (int t = 0; t < 3; t++)
#pragma unroll
      for (int u = 0; u < 4; u++)
        c[t][u] = (f32x4){ev[u], ev[u], ev[u], ev[u]};
    const int r7 = col & 7;
#pragma unroll
    for (int m = 0; m < 2; m++) {
#pragma unroll
      for (int u = 0; u < 4; u++) {
        int row = u * 16 + col;
        int s0 = m * 8 + ((2 * quad) ^ r7);
        int s1 = m * 8 + ((2 * quad + 1) ^ r7);
        int4 b0 = *(const int4*)(bbase + row * 256 + s0 * 16);
        int4 b1 = *(const int4*)(bbase + row * 256 + s1 * 16);
        i32x8 bfr = (i32x8){b0.x, b0.y, b0.z, b0.w, b1.x, b1.y, b1.z, b1.w};
#pragma unroll
        for (int t = 0; t < 3; t++) c[t][u] = mfma_mx(af[t][m], bfr, c[t][u]);
      }
    }
#pragma unroll
    for (int t = 0; t < 3; t++)
#pragma unroll
      for (int r = 0; r < 4; r++) {
        u32 k0 = (__float_as_uint(c[t][0][r]) & 0xFFFFFFC0u) | (u32)(st * 4 + 0);
        u32 k1 = (__float_as_uint(c[t][1][r]) & 0xFFFFFFC0u) | (u32)(st * 4 + 1);
        u32 k2 = (__float_as_uint(c[t][2][r]) & 0xFFFFFFC0u) | (u32)(st * 4 + 2);
        u32 k3 = (__float_as_uint(c[t][3][r]) & 0xFFFFFFC0u) | (u32)(st * 4 + 3);
        u32 a = k0 < k1 ? k0 : k1;
        u32 bm_ = k2 < k3 ? k2 : k3;
        u32 m_ = a < bm_ ? a : bm_;
        best[t][r] = m_ < best[t][r] ? m_ : best[t][r];
      }
  };

  stage_load(0, 0);
  for (int st = 0; st < 16; st++) {
    __syncthreads();
    if (st < 15) stage_load(st + 1, (st + 1) & 1);
    compute(st, st & 1);
  }

#pragma unroll
  for (int t = 0; t < 3; t++)
#pragma unroll
    for (int r = 0; r < 4; r++) {
      u32 key = best[t][r];
      int cw = col;
#pragma unroll
      for (int off = 1; off < 16; off <<= 1) {
        u32 ok = (u32)__shfl_xor((int)key, off, 64);
        int oc = __shfl_xor(cw, off, 64);
        if (ok < key) { key = ok; cw = oc; }
      }
      if (col == 0) {
        int token = tw + t * 16 + quad * 4 + r;
        pval[token * GROUPS + g] = __uint_as_float(key & 0xFFFFFFC0u);
        pidx[token * GROUPS + g] = g * GSIZE + (int)(key & 63u) * 16 + cw;
      }
    }
}

// ---------------- decoder GEMM with fused gather + loss ----------------
// out = cb[idx] @ dec_wT^T + dec_b. grid (144,4), 64 tokens x 256 cols.
// Phase 0: per-token argmin combine (4 lanes/token). Phase 1: K-loop; A-side
// gathers cb rows f32 (LLC) -> bf16 -> LDS; zqb never materialized.
// by==0 blocks also accumulate the loss partial (vs fp8 z).
__global__ __launch_bounds__(256) void k_dec(const float* __restrict__ cb,
                                             const float* __restrict__ pval,
                                             const int* __restrict__ pidx,
                                             const u8* __restrict__ zb8,
                                             const bf16* __restrict__ wT,
                                             const float* __restrict__ bias,
                                             float* __restrict__ out,
                                             float* __restrict__ lpart) {
  __shared__ __align__(16) bf16 As[2][64 * 32];
  __shared__ __align__(16) bf16 Bs[2][256 * 32];
  __shared__ int idxL[64];
  __shared__ float lsred[4];
  const int tid = threadIdx.x;
  const int wid = tid >> 6, lane = tid & 63;
  const int col = lane & 15, quad = lane >> 4;
  const int wm = (wid >> 1) * 32, wn = (wid & 1) * 128;
  const int bm = blockIdx.x * 64, bn = blockIdx.y * 256;
  const bool do_loss = (blockIdx.y == 0);

  // ---- phase 0: combine the 16 group candidates for this block's 64 tokens
  {
    int tl = tid >> 2, j0 = tid & 3;
    float v = 3.4e38f;
    int idx = 0;
#pragma unroll
    for (int jj = 0; jj < 4; jj++) {
      int grp = j0 * 4 + jj;
      float ov = pval[(bm + tl) * GROUPS + grp];
      int oi = pidx[(bm + tl) * GROUPS + grp];
      if (ov < v || (ov == v && oi < idx)) { v = ov; idx = oi; }
    }
#pragma unroll
    for (int off = 1; off < 4; off <<= 1) {
      float ov = __shfl_xor(v, off, 64);
      int oi = __shfl_xor(idx, off, 64);
      if (ov < v || (ov == v && oi < idx)) { v = ov; idx = oi; }
    }
    if (j0 == 0) idxL[tl] = idx;
  }
  __syncthreads();

  const int arow = tid >> 2, ags = tid & 3;
  const int ridx = idxL[arow];
  float lacc = 0.f;
  f32x4 acc[2][8] = {};

  float4 q0, q1;
  auto loadA = [&](int kc) {
    const float* p = cb + (size_t)ridx * EDIM + kc + ags * 8;
    q0 = *(const float4*)p;
    q1 = *(const float4*)(p + 4);
    if (do_loss) {
      u32 zw0 = *(const u32*)(zb8 + (size_t)(bm + arow) * EDIM + kc + ags * 8);
      u32 zw1 = *(const u32*)(zb8 + (size_t)(bm + arow) * EDIM + kc + ags * 8 + 4);
      float d0 = q0.x - __builtin_amdgcn_cvt_f32_fp8(zw0, 0);
      float d1 = q0.y - __builtin_amdgcn_cvt_f32_fp8(zw0, 1);
      float d2 = q0.z - __builtin_amdgcn_cvt_f32_fp8(zw0, 2);
      float d3 = q0.w - __builtin_amdgcn_cvt_f32_fp8(zw0, 3);
      float d4 = q1.x - __builtin_amdgcn_cvt_f32_fp8(zw1, 0);
      float d5 = q1.y - __builtin_amdgcn_cvt_f32_fp8(zw1, 1);
      float d6 = q1.z - __builtin_amdgcn_cvt_f32_fp8(zw1, 2);
      float d7 = q1.w - __builtin_amdgcn_cvt_f32_fp8(zw1, 3);
      lacc += d0 * d0 + d1 * d1 + d2 * d2 + d3 * d3 +
              d4 * d4 + d5 * d5 + d6 * d6 + d7 * d7;
    }
  };
  auto writeA = [&](int bb) {
    bf16x8 o = {(bf16)q0.x, (bf16)q0.y, (bf16)q0.z, (bf16)q0.w,
                (bf16)q1.x, (bf16)q1.y, (bf16)q1.z, (bf16)q1.w};
    *(bf16x8*)((char*)&As[bb][0] + (arow * 4 + (ags ^ (arow & 3))) * 16) = o;
  };
  auto stageB = [&](int kc, int bb) {
#pragma unroll
    for (int j = 0; j < 4; j++) {
      int slot = wid * 256 + j * 64 + lane;
      int row = slot >> 2;
      int gg = (slot & 3) ^ (row & 3);
      async_load16(wT + (size_t)(bn + row) * EDIM + kc + gg * 8,
                   (char*)&Bs[bb][0] + wid * 4096 + j * 1024);
    }
  };

  loadA(0);
  writeA(0);
  stageB(0, 0);
  for (int it = 0; it < 8; it++) {
    int cbuf = it & 1, nbuf = cbuf ^ 1;
    __syncthreads();
    if (it < 7) {
      loadA((it + 1) * 32);
      stageB((it + 1) * 32, nbuf);
    }
    bf16x8 afr[2], bfr[8];
#pragma unroll
    for (int t = 0; t < 2; t++) {
      int row = wm + t * 16 + col;
      afr[t] = *(const bf16x8*)((const char*)&As[cbuf][0] +
                                (row * 4 + (quad ^ (row & 3))) * 16);
    }
#pragma unroll
    for (int u = 0; u < 8; u++) {
      int row = wn + u * 16 + col;
      bfr[u] = *(const bf16x8*)((const char*)&Bs[cbuf][0] +
                                (row * 4 + (quad ^ (row & 3))) * 16);
    }
#pragma unroll
    for (int t = 0; t < 2; t++)
#pragma unroll
      for (int u = 0; u < 8; u++) acc[t][u] = mfma16(afr[t], bfr[u], acc[t][u]);
    if (it < 7) writeA(nbuf);
  }

#pragma unroll
  for (int u = 0; u < 8; u++) {
    int n = bn + wn + u * 16 + col;
    float bv = bias[n];
#pragma unroll
    for (int t = 0; t < 2; t++)
#pragma unroll
      for (int r = 0; r < 4; r++) {
        int m = bm + wm + t * 16 + quad * 4 + r;
        out[(size_t)m * SRC + n] = acc[t][u][r] + bv;
      }
  }

  if (do_loss) {
#pragma unroll
    for (int off = 32; off; off >>= 1) lacc += __shfl_xor(lacc, off, 64);
    if (lane == 0) lsred[wid] = lacc;
    __syncthreads();
    if (tid == 0) lpart[blockIdx.x] = lsred[0] + lsred[1] + lsred[2] + lsred[3];
  }
}

__global__ __launch_bounds__(256) void k_loss(const float* __restrict__ lpart,
                                              float* __restrict__ outl) {
  float s = 0.f;
  if (threadIdx.x < NBLK_LOSS) s = lpart[threadIdx.x];
#pragma unroll
  for (int off = 32; off; off >>= 1) s += __shfl_xor(s, off, 64);
  __shared__ float ls[4];
  int wv = threadIdx.x >> 6;
  if ((threadIdx.x & 63) == 0) ls[wv] = s;
  __syncthreads();
  if (threadIdx.x == 0) *outl = 1.25f * (ls[0] + ls[1] + ls[2] + ls[3]) / LOSS_DENOM;
}

// ---------------- launch ----------------
extern "C" void kernel_launch(void* const* d_in, const int* in_sizes, int n_in,
                              void* d_out, int out_size, void* d_ws, size_t ws_size,
                              hipStream_t stream) {
  const float* x = (const float*)d_in[0];
  const float* enc_w = (const float*)d_in[1];
  const float* enc_b = (const float*)d_in[2];
  const float* cb = (const float*)d_in[3];
  const float* dec_w = (const float*)d_in[4];
  const float* dec_b = (const float*)d_in[5];
  float* out = (float*)d_out;
  float* out_loss = out + (size_t)N_TOK * SRC;

  char* ws = (char*)d_ws;
  bf16* enc_wT = (bf16*)(ws + 0);          //   524,288 B
  bf16* dec_wT = (bf16*)(ws + 524288);     //   524,288 B
  u8* zb8 = (u8*)(ws + 1048576);           // 2,359,296 B
  u32* cbb8 = (u32*)(ws + 3407872);        // 4,194,304 B
  float* e2s = (float*)(ws + 7602176);     //    65,536 B
  float* pval = (float*)(ws + 7667712);    //   589,824 B
  int* pidx = (int*)(ws + 8257536);        //   589,824 B
  float* lpart = (float*)(ws + 8847360);   //       576 B   (~8.8 MiB)

  k_prep<<<4224, 256, 0, stream>>>(enc_w, dec_w, cb, enc_wT, dec_wT, cbb8, e2s);
  // encoder: 64x64 tiles, grid 576, barrier-drain-safe A loads
  k_enc<<<dim3(144, 4), 256, 0, stream>>>(x, enc_wT, enc_b, zb8);
  // fused MX-fp8 K=128 distance + argmin: 768 blocks = exactly 3/CU
  k_argmin<<<dim3(48, GROUPS), 256, 0, stream>>>(zb8, (const u8*)cbb8, e2s, pval, pidx);
  // decoder with fused gather + loss partials: 64x256 tiles, grid 576
  k_dec<<<dim3(144, 4), 256, 0, stream>>>(cb, pval, pidx, zb8, dec_wT, dec_b, out, lpart);
  k_loss<<<1, 256, 0, stream>>>(lpart, out_loss);
}